// Round 3
// baseline (287.793 us; speedup 1.0000x reference)
//
#include <hip/hip_runtime.h>

typedef unsigned short u16;
typedef unsigned int   u32;

using bf16x8 = __attribute__((ext_vector_type(8))) __bf16;
using bf16x4 = __attribute__((ext_vector_type(4))) __bf16;
using f32x4  = __attribute__((ext_vector_type(4))) float;
using s16x4  = __attribute__((ext_vector_type(4))) short;

#define NH    16
#define DKH   64
#define SEQ   2048
#define BAT   2
#define DMOD  1024

// 0.125 (1/sqrt(dk)) * log2(e): scores in log2 domain -> p = exp2(s)
#define QSCALE 0.18033688011112042f

__device__ __forceinline__ u16 f2bf(float f) {
  union { float f; u32 u; } v; v.f = f;
  u32 r = v.u + 0x7fffu + ((v.u >> 16) & 1u);
  return (u16)(r >> 16);
}

__device__ __forceinline__ u32 pack2bf(float a, float b) {
  union { float f; u32 u; } x, y; x.f = a; y.f = b;
  u32 ua = x.u + 0x7fffu + ((x.u >> 16) & 1u);
  u32 ub = y.u + 0x7fffu + ((y.u >> 16) & 1u);
  return __builtin_amdgcn_perm(ub, ua, 0x07060302u);
}

// compiler emits v_cvt_pk_bf16_f32 pairs
__device__ __forceinline__ s16x4 pk4bf(float a, float b, float c, float d) {
  union { bf16x4 bv; s16x4 sv; } u;
  u.bv[0] = (__bf16)a; u.bv[1] = (__bf16)b; u.bv[2] = (__bf16)c; u.bv[3] = (__bf16)d;
  return u.sv;
}

#if __has_builtin(__builtin_amdgcn_exp2f)
#define EXP2(x) __builtin_amdgcn_exp2f(x)
#else
#define EXP2(x) exp2f(x)
#endif

#if __has_builtin(__builtin_amdgcn_mfma_f32_16x16x16bf16_1k)
__device__ __forceinline__ f32x4 mfma16(s16x4 a, s16x4 b, f32x4 c) {
  return __builtin_amdgcn_mfma_f32_16x16x16bf16_1k(a, b, c, 0, 0, 0);
}
#else
__device__ __forceinline__ f32x4 mfma16(s16x4 a, s16x4 b, f32x4 c) {
  f32x4 d;
  asm volatile("v_mfma_f32_16x16x16_bf16 %0, %1, %2, %3\n\ts_nop 7\n\ts_nop 7"
               : "=v"(d) : "v"(a), "v"(b), "v"(c));
  return d;
}
#endif

// ---------------- fused 4x weight transpose + fp32->bf16 ----------------
__global__ __launch_bounds__(256) void transpose_all(const float* __restrict__ Wq,
                                                     const float* __restrict__ Wk,
                                                     const float* __restrict__ Wv,
                                                     const float* __restrict__ Wo,
                                                     u16* __restrict__ Wt) {
  __shared__ u16 t[32][33];
  const float* W = blockIdx.z == 0 ? Wq : blockIdx.z == 1 ? Wk : blockIdx.z == 2 ? Wv : Wo;
  u16* o = Wt + (size_t)blockIdx.z * DMOD * DMOD;
  int bx = blockIdx.x * 32, by = blockIdx.y * 32;
  int x = threadIdx.x, y = threadIdx.y;
  #pragma unroll
  for (int i = 0; i < 32; i += 8)
    t[y + i][x] = f2bf(W[(size_t)(by + y + i) * DMOD + bx + x]);
  __syncthreads();
  #pragma unroll
  for (int i = 0; i < 32; i += 8)
    o[(size_t)(bx + y + i) * DMOD + by + x] = t[x][y + i];
}

// ---------------- x fp32 -> bf16 ----------------
__global__ __launch_bounds__(256) void convert_x(const float* __restrict__ x,
                                                 u16* __restrict__ xb) {
  size_t i = ((size_t)blockIdx.x * 256 + threadIdx.x) * 8;
  float4 f0 = *(const float4*)(x + i);
  float4 f1 = *(const float4*)(x + i + 4);
  uint4 o;
  o.x = pack2bf(f0.x, f0.y); o.y = pack2bf(f0.z, f0.w);
  o.z = pack2bf(f1.x, f1.y); o.w = pack2bf(f1.z, f1.w);
  *(uint4*)(xb + i) = o;
}

// -------- QKV GEMM: [4096x1024]*[3072x1024]^T, BK=32, reg-prefetch, padded LDS --------
__global__ __launch_bounds__(256, 3) void gemm_qkv(const u16* __restrict__ A,
                                                   const u16* __restrict__ Bt,
                                                   u16* __restrict__ Qo,
                                                   u16* __restrict__ Ko,
                                                   u16* __restrict__ Vo) {
  __shared__ __align__(16) u16 As[128 * 40];
  __shared__ __align__(16) u16 Bs[128 * 40];
  const int tid  = threadIdx.x;
  const int lane = tid & 63, wv = tid >> 6;
  const int wm   = wv >> 1, wn = wv & 1;
  const int lrow = lane & 15, quad = lane >> 4;
  const int tileM = blockIdx.x * 128, tileN = blockIdx.y * 128;
  const int r0 = tid >> 2, c0 = (tid & 3) * 8;
  const int r1 = r0 + 64;

  const f32x4 fz = {0.f, 0.f, 0.f, 0.f};
  f32x4 acc[4][4];
  #pragma unroll
  for (int i = 0; i < 4; ++i)
    #pragma unroll
    for (int j = 0; j < 4; ++j) acc[i][j] = fz;

  uint4 a0 = *(const uint4*)(&A [(size_t)(tileM + r0) * DMOD + c0]);
  uint4 a1 = *(const uint4*)(&A [(size_t)(tileM + r1) * DMOD + c0]);
  uint4 b0 = *(const uint4*)(&Bt[(size_t)(tileN + r0) * DMOD + c0]);
  uint4 b1 = *(const uint4*)(&Bt[(size_t)(tileN + r1) * DMOD + c0]);

  for (int kt = 0; kt < DMOD; kt += 32) {
    __syncthreads();
    *(uint4*)(&As[r0 * 40 + c0]) = a0;
    *(uint4*)(&As[r1 * 40 + c0]) = a1;
    *(uint4*)(&Bs[r0 * 40 + c0]) = b0;
    *(uint4*)(&Bs[r1 * 40 + c0]) = b1;
    if (kt + 32 < DMOD) {
      a0 = *(const uint4*)(&A [(size_t)(tileM + r0) * DMOD + kt + 32 + c0]);
      a1 = *(const uint4*)(&A [(size_t)(tileM + r1) * DMOD + kt + 32 + c0]);
      b0 = *(const uint4*)(&Bt[(size_t)(tileN + r0) * DMOD + kt + 32 + c0]);
      b1 = *(const uint4*)(&Bt[(size_t)(tileN + r1) * DMOD + kt + 32 + c0]);
    }
    __syncthreads();
    bf16x8 af[4], bfr[4];
    #pragma unroll
    for (int mt = 0; mt < 4; ++mt)
      af[mt] = *(const bf16x8*)(&As[(wm * 64 + mt * 16 + lrow) * 40 + quad * 8]);
    #pragma unroll
    for (int nt = 0; nt < 4; ++nt)
      bfr[nt] = *(const bf16x8*)(&Bs[(wn * 64 + nt * 16 + lrow) * 40 + quad * 8]);
    #pragma unroll
    for (int mt = 0; mt < 4; ++mt)
      #pragma unroll
      for (int nt = 0; nt < 4; ++nt)
        acc[mt][nt] = __builtin_amdgcn_mfma_f32_16x16x32_bf16(af[mt], bfr[nt],
                                                              acc[mt][nt], 0, 0, 0);
  }

  #pragma unroll
  for (int mt = 0; mt < 4; ++mt) {
    #pragma unroll
    for (int nt = 0; nt < 4; ++nt) {
      int gm0 = tileM + wm * 64 + mt * 16 + quad * 4;
      int gn  = tileN + wn * 64 + nt * 16 + lrow;
      int which = gn >> 10, col = gn & 1023;
      int bb = gm0 >> 11, srw0 = gm0 & (SEQ - 1);
      int hh = col >> 6, dki = col & (DKH - 1);
      size_t bhi = (size_t)(bb * NH + hh);
      if (which == 0) {
        #pragma unroll
        for (int r = 0; r < 4; ++r)
          Qo[(bhi * SEQ + srw0 + r) * DKH + dki] = f2bf(acc[mt][nt][r] * QSCALE);
      } else if (which == 1) {
        #pragma unroll
        for (int r = 0; r < 4; ++r)
          Ko[(bhi * SEQ + srw0 + r) * DKH + dki] = f2bf(acc[mt][nt][r]);
      } else {
        uint2 pk;
        pk.x = pack2bf(acc[mt][nt][0], acc[mt][nt][1]);
        pk.y = pack2bf(acc[mt][nt][2], acc[mt][nt][3]);
        *(uint2*)(&Vo[(((bhi * (SEQ / 4)) + (srw0 >> 2)) * DKH + dki) * 4]) = pk;
      }
    }
  }
}

// -------- out GEMM: [4096x1024]*[1024x1024]^T -> fp32, 128x64, BK=32, reg-prefetch -----
__global__ __launch_bounds__(256, 3) void gemm_out(const u16* __restrict__ A,
                                                   const u16* __restrict__ Bt,
                                                   float* __restrict__ Co) {
  __shared__ __align__(16) u16 As[128 * 40];
  __shared__ __align__(16) u16 Bs[64 * 40];
  const int tid  = threadIdx.x;
  const int lane = tid & 63, wv = tid >> 6;
  const int wm   = wv & 1, wn = wv >> 1;
  const int lrow = lane & 15, quad = lane >> 4;
  const int tileM = blockIdx.x * 128, tileN = blockIdx.y * 64;
  const int r0 = tid >> 2, c0 = (tid & 3) * 8;
  const int r1 = r0 + 64;

  const f32x4 fz = {0.f, 0.f, 0.f, 0.f};
  f32x4 acc[4][2];
  #pragma unroll
  for (int i = 0; i < 4; ++i) { acc[i][0] = fz; acc[i][1] = fz; }

  uint4 a0 = *(const uint4*)(&A [(size_t)(tileM + r0) * DMOD + c0]);
  uint4 a1 = *(const uint4*)(&A [(size_t)(tileM + r1) * DMOD + c0]);
  uint4 b0 = *(const uint4*)(&Bt[(size_t)(tileN + (r0 & 63)) * DMOD + c0]);

  for (int kt = 0; kt < DMOD; kt += 32) {
    __syncthreads();
    *(uint4*)(&As[r0 * 40 + c0]) = a0;
    *(uint4*)(&As[r1 * 40 + c0]) = a1;
    if (r0 < 64) *(uint4*)(&Bs[r0 * 40 + c0]) = b0;
    if (kt + 32 < DMOD) {
      a0 = *(const uint4*)(&A [(size_t)(tileM + r0) * DMOD + kt + 32 + c0]);
      a1 = *(const uint4*)(&A [(size_t)(tileM + r1) * DMOD + kt + 32 + c0]);
      b0 = *(const uint4*)(&Bt[(size_t)(tileN + (r0 & 63)) * DMOD + kt + 32 + c0]);
    }
    __syncthreads();
    bf16x8 af[4], bfr[2];
    #pragma unroll
    for (int mt = 0; mt < 4; ++mt)
      af[mt] = *(const bf16x8*)(&As[(wm * 64 + mt * 16 + lrow) * 40 + quad * 8]);
    #pragma unroll
    for (int nt = 0; nt < 2; ++nt)
      bfr[nt] = *(const bf16x8*)(&Bs[(wn * 32 + nt * 16 + lrow) * 40 + quad * 8]);
    #pragma unroll
    for (int mt = 0; mt < 4; ++mt)
      #pragma unroll
      for (int nt = 0; nt < 2; ++nt)
        acc[mt][nt] = __builtin_amdgcn_mfma_f32_16x16x32_bf16(af[mt], bfr[nt],
                                                              acc[mt][nt], 0, 0, 0);
  }

  #pragma unroll
  for (int mt = 0; mt < 4; ++mt)
    #pragma unroll
    for (int nt = 0; nt < 2; ++nt)
      #pragma unroll
      for (int r = 0; r < 4; ++r) {
        int gm = tileM + wm * 64 + mt * 16 + quad * 4 + r;
        int gn = tileN + wn * 32 + nt * 16 + lrow;
        Co[(size_t)gm * DMOD + gn] = acc[mt][nt][r];
      }
}

// ---------------- causal flash attention: S^T form, parity k-split ----------------
// Round-3: 256-thread blocks (4 waves x 2 strips = 128-row q-tile), double-buffered
// K/V (70 KB -> 2 blocks/CU). Grid (32 bh, 16): pr = y&7, par = y>>3. Block handles
// q-tiles {pr, 15-pr} SEQUENTIALLY but only k-tiles j == par (mod 2): every block is
// exactly 8 or 9 iters; co-resident pair (same pr, both parities) = 17 iters/CU with
// 2-block overlap sustained -> no solo tail (round-1 defect b).
// Per-m interleaved softmax: sacc is 2 f32x4 (8 regs) instead of 64 -> no scratch
// spill (round-1/2 defect a; round-2's 62 MB WRITE_SIZE was spill traffic).
// Parities combine via fp32 partials + last-arriver protocol (device-scope
// atomic + threadfence, XCD-safe).
#define KP 72
#define VP 132
#define OP 68

__global__ __launch_bounds__(256, 2) void attn_k(const u16* __restrict__ Q,
                                                 const u16* __restrict__ Kg,
                                                 const u16* __restrict__ Vg,
                                                 u16* __restrict__ Og,
                                                 float* __restrict__ Poacc,
                                                 float* __restrict__ Plsum,
                                                 u32* __restrict__ Pcnt) {
  __shared__ __align__(16) u16 KsA[128 * KP];
  __shared__ __align__(16) u16 VsA[64 * VP];
  __shared__ __align__(16) u16 KsB[128 * KP];
  __shared__ __align__(16) u16 VsB[64 * VP];
  __shared__ u32 flagsh;

  const int tid  = threadIdx.x;
  const int lane = tid & 63, w = tid >> 6;          // w in 0..3
  const int lrow = lane & 15, quad = lane >> 4;
  const int bh = blockIdx.x;
  const int y  = blockIdx.y;
  const int pr  = y & 7;                            // pair index
  const int par = y >> 3;                           // k-parity 0/1
  const int b = bh >> 4, h = bh & 15;

  const u16* Qbh = Q  + (size_t)bh * SEQ * DKH;
  const u16* Kbh = Kg + (size_t)bh * SEQ * DKH;
  const u16* Vbh = Vg + (size_t)bh * SEQ * DKH;     // [s/4][dk][4]

  const f32x4 fz = {0.f, 0.f, 0.f, 0.f};
  int cur = 0;

  for (int half = 0; half < 2; ++half) {
    const int qt = half ? (15 - pr) : pr;           // 128-row q-tile index

    // Q fragments: wave w owns strips ss=2w, 2w+1 (rows qt*128 + ss*16 + lrow)
    bf16x8 bq[2][2];
    #pragma unroll
    for (int s = 0; s < 2; ++s)
      #pragma unroll
      for (int kk = 0; kk < 2; ++kk)
        bq[s][kk] = *(const bf16x8*)(&Qbh[(size_t)(qt * 128 + (2 * w + s) * 16 + lrow) * DKH
                                          + kk * 32 + quad * 8]);

    f32x4 oacc[2][4];
    #pragma unroll
    for (int s = 0; s < 2; ++s)
      #pragma unroll
      for (int d = 0; d < 4; ++d) oacc[s][d] = fz;
    float lsum[2] = {0.f, 0.f};

    // prime prefetch with first k-tile of this half (if any)
    uint4 kreg[4], vreg[4];
    if (par <= qt) {
      #pragma unroll
      for (int k = 0; k < 4; ++k) {
        int ci = k * 256 + tid;
        kreg[k] = *(const uint4*)(&Kbh[(size_t)(par * 128 + (ci >> 3)) * DKH + (ci & 7) * 8]);
        vreg[k] = *(const uint4*)(&Vbh[(size_t)(par * 32 + (ci >> 5)) * 256 + (ci & 31) * 8]);
      }
    }

    for (int j = par; j <= qt; j += 2) {
      u16* Ks = cur ? KsB : KsA;
      u16* Vs = cur ? VsB : VsA;

      #pragma unroll
      for (int k = 0; k < 4; ++k) {
        int ci = k * 256 + tid;
        *(uint4*)(&Ks[(ci >> 3) * KP + (ci & 7) * 8]) = kreg[k];
        int sq = ci >> 5, dkp = ci & 31;
        union { uint4 q; uint2 d[2]; } vv; vv.q = vreg[k];
        *(uint2*)(&Vs[(2 * dkp)     * VP + 4 * sq]) = vv.d[0];
        *(uint2*)(&Vs[(2 * dkp + 1) * VP + 4 * sq]) = vv.d[1];
      }

      if (j + 2 <= qt) {
        const int jn = j + 2;
        #pragma unroll
        for (int k = 0; k < 4; ++k) {
          int ci = k * 256 + tid;
          kreg[k] = *(const uint4*)(&Kbh[(size_t)(jn * 128 + (ci >> 3)) * DKH + (ci & 7) * 8]);
          vreg[k] = *(const uint4*)(&Vbh[(size_t)(jn * 32 + (ci >> 5)) * 256 + (ci & 31) * 8]);
        }
      }

      __syncthreads();

      if (j < qt) {
        // full k-tile, per-m interleave: sacc is just 2 f32x4 at a time
        #pragma unroll
        for (int m = 0; m < 8; ++m) {
          f32x4 s0 = fz, s1 = fz;
          #pragma unroll
          for (int kk = 0; kk < 2; ++kk) {
            bf16x8 ak = *(const bf16x8*)(&Ks[(m * 16 + lrow) * KP + kk * 32 + quad * 8]);
            s0 = __builtin_amdgcn_mfma_f32_16x16x32_bf16(ak, bq[0][kk], s0, 0, 0, 0);
            s1 = __builtin_amdgcn_mfma_f32_16x16x32_bf16(ak, bq[1][kk], s1, 0, 0, 0);
          }
          float p00 = EXP2(s0[0]), p01 = EXP2(s0[1]), p02 = EXP2(s0[2]), p03 = EXP2(s0[3]);
          float p10 = EXP2(s1[0]), p11 = EXP2(s1[1]), p12 = EXP2(s1[2]), p13 = EXP2(s1[3]);
          lsum[0] += (p00 + p01) + (p02 + p03);
          lsum[1] += (p10 + p11) + (p12 + p13);
          s16x4 pk0 = pk4bf(p00, p01, p02, p03);
          s16x4 pk1 = pk4bf(p10, p11, p12, p13);
          #pragma unroll
          for (int d = 0; d < 4; ++d) {
            s16x4 av = *(const s16x4*)(&Vs[(d * 16 + lrow) * VP + m * 16 + quad * 4]);
            oacc[0][d] = mfma16(av, pk0, oacc[0][d]);
            oacc[1][d] = mfma16(av, pk1, oacc[1][d]);
          }
        }
      } else {
        // diagonal k-tile (owned by parity qt&1): per-strip triangular
        #pragma unroll
        for (int s = 0; s < 2; ++s) {
          const int ss = 2 * w + s;
          for (int m = 0; m < ss; ++m) {
            f32x4 sv = fz;
            #pragma unroll
            for (int kk = 0; kk < 2; ++kk) {
              bf16x8 ak = *(const bf16x8*)(&Ks[(m * 16 + lrow) * KP + kk * 32 + quad * 8]);
              sv = __builtin_amdgcn_mfma_f32_16x16x32_bf16(ak, bq[s][kk], sv, 0, 0, 0);
            }
            float p0 = EXP2(sv[0]), p1 = EXP2(sv[1]), p2 = EXP2(sv[2]), p3 = EXP2(sv[3]);
            lsum[s] += (p0 + p1) + (p2 + p3);
            s16x4 pk = pk4bf(p0, p1, p2, p3);
            #pragma unroll
            for (int d = 0; d < 4; ++d) {
              s16x4 av = *(const s16x4*)(&Vs[(d * 16 + lrow) * VP + m * 16 + quad * 4]);
              oacc[s][d] = mfma16(av, pk, oacc[s][d]);
            }
          }
          { // m == ss : masked diagonal strip (k > q -> 0)
            f32x4 sv = fz;
            #pragma unroll
            for (int kk = 0; kk < 2; ++kk) {
              bf16x8 ak = *(const bf16x8*)(&Ks[(ss * 16 + lrow) * KP + kk * 32 + quad * 8]);
              sv = __builtin_amdgcn_mfma_f32_16x16x32_bf16(ak, bq[s][kk], sv, 0, 0, 0);
            }
            float p[4];
            #pragma unroll
            for (int r = 0; r < 4; ++r)
              p[r] = (quad * 4 + r > lrow) ? 0.f : EXP2(sv[r]);
            lsum[s] += (p[0] + p[1]) + (p[2] + p[3]);
            s16x4 pk = pk4bf(p[0], p[1], p[2], p[3]);
            #pragma unroll
            for (int d = 0; d < 4; ++d) {
              s16x4 av = *(const s16x4*)(&Vs[(d * 16 + lrow) * VP + ss * 16 + quad * 4]);
              oacc[s][d] = mfma16(av, pk, oacc[s][d]);
            }
          }
        }
      }
      cur ^= 1;
    }

    // ------- epilogue: partial write + last-arriver combine -------
    float ls[2];
    #pragma unroll
    for (int s = 0; s < 2; ++s) {
      float v = lsum[s];
      v += __shfl_xor(v, 16, 64);
      v += __shfl_xor(v, 32, 64);
      ls[s] = v;
    }

    const int tile = bh * 16 + qt;                  // 0..511
    float* myO = Poacc + ((size_t)tile * 2 + par) * (128 * 64);
    float* myL = Plsum + ((size_t)tile * 2 + par) * 128;

    #pragma unroll
    for (int s = 0; s < 2; ++s) {
      int row = (2 * w + s) * 16 + lrow;
      #pragma unroll
      for (int d = 0; d < 4; ++d)
        *(f32x4*)(&myO[row * 64 + d * 16 + quad * 4]) = oacc[s][d];
      if (quad == 0) myL[row] = ls[s];
    }

    __syncthreads();                                // all stores issued+drained (vmcnt in barrier)
    if (tid == 0) {
      __threadfence();                              // device-scope release (XCD L2 writeback)
      flagsh = atomicAdd(&Pcnt[tile], 1);
    }
    __syncthreads();

    if (flagsh == 1) {
      __threadfence();                              // acquire: see partner's partial
      const float* oO = Poacc + ((size_t)tile * 2 + (par ^ 1)) * (128 * 64);
      const float* oL = Plsum + ((size_t)tile * 2 + (par ^ 1)) * 128;
      u16* Osr = KsA;                               // 128 x OP staging
      #pragma unroll
      for (int s = 0; s < 2; ++s) {
        int row = (2 * w + s) * 16 + lrow;
        float inv = 1.f / (ls[s] + oL[row]);
        #pragma unroll
        for (int d = 0; d < 4; ++d) {
          f32x4 ov = *(const f32x4*)(&oO[row * 64 + d * 16 + quad * 4]);
          float o0 = (oacc[s][d][0] + ov[0]) * inv;
          float o1 = (oacc[s][d][1] + ov[1]) * inv;
          float o2 = (oacc[s][d][2] + ov[2]) * inv;
          float o3 = (oacc[s][d][3] + ov[3]) * inv;
          uint2 pkk;
          pkk.x = pack2bf(o0, o1);
          pkk.y = pack2bf(o2, o3);
          *(uint2*)(&Osr[row * OP + d * 16 + quad * 4]) = pkk;
        }
      }
      __syncthreads();
      #pragma unroll
      for (int k = 0; k < 4; ++k) {
        int c = k * 256 + tid;                      // 1024 chunks = 128 rows x 128B
        int row = c >> 3, ch = c & 7;
        uint4 v = *(const uint4*)(&Osr[row * OP + ch * 8]);
        *(uint4*)(&Og[(size_t)(b * SEQ + qt * 128 + row) * DMOD + h * DKH + ch * 8]) = v;
      }
      __syncthreads();                              // KsA free before next half stages into it
    }
  }
}

// ---------------- launch ----------------
extern "C" void kernel_launch(void* const* d_in, const int* in_sizes, int n_in,
                              void* d_out, int out_size, void* d_ws, size_t ws_size,
                              hipStream_t stream) {
  const float* x  = (const float*)d_in[0];
  const float* Wq = (const float*)d_in[1];
  const float* Wk = (const float*)d_in[2];
  const float* Wv = (const float*)d_in[3];
  const float* Wo = (const float*)d_in[4];

  u16* ws = (u16*)d_ws;
  const size_t WSZ = (size_t)DMOD * DMOD;
  const size_t TSZ = (size_t)BAT * NH * SEQ * DKH;
  u16* Wt  = ws;                 // 4 transposed weights
  u16* Wto = Wt + 3 * WSZ;
  u16* xb  = Wt + 4 * WSZ;       // x bf16; dead after QKV -> reused as Ob
  u16* Qb  = xb + TSZ;
  u16* Kb  = Qb + TSZ;
  u16* Vb  = Kb + TSZ;           // [b,h,s/4,dk,4]
  u16* Ob  = xb;

  // attention parity-split partials (after Vb), 256B aligned
  uintptr_t pp = ((uintptr_t)(Vb + TSZ) + 255) & ~(uintptr_t)255;
  float* Poacc = (float*)pp;                                  // 512*2*128*64 f32 = 33.5 MB
  float* Plsum = Poacc + (size_t)512 * 2 * 128 * 64;          // 512*2*128 f32
  u32*   Pcnt  = (u32*)(Plsum + (size_t)512 * 2 * 128);       // 512 u32

  hipMemsetAsync(Pcnt, 0, 512 * sizeof(u32), stream);

  transpose_all<<<dim3(32, 32, 4), dim3(32, 8), 0, stream>>>(Wq, Wk, Wv, Wo, Wt);
  convert_x<<<dim3(2048), 256, 0, stream>>>(x, xb);

  gemm_qkv<<<dim3(32, 24), 256, 0, stream>>>(xb, Wt, Qb, Kb, Vb);

  attn_k<<<dim3(32, 16), 256, 0, stream>>>(Qb, Kb, Vb, Ob, Poacc, Plsum, Pcnt);

  gemm_out<<<dim3(32, 16), 256, 0, stream>>>(Ob, Wto, (float*)d_out);
}

// Round 4
// 181.148 us; speedup vs baseline: 1.5887x; 1.5887x over previous
//
#include <hip/hip_runtime.h>

typedef unsigned short u16;
typedef unsigned int   u32;

using bf16x8 = __attribute__((ext_vector_type(8))) __bf16;
using bf16x4 = __attribute__((ext_vector_type(4))) __bf16;
using f32x4  = __attribute__((ext_vector_type(4))) float;
using s16x4  = __attribute__((ext_vector_type(4))) short;

#define NH    16
#define DKH   64
#define SEQ   2048
#define BAT   2
#define DMOD  1024

// 0.125 (1/sqrt(dk)) * log2(e): scores in log2 domain -> p = exp2(s)
#define QSCALE 0.18033688011112042f

__device__ __forceinline__ u16 f2bf(float f) {
  union { float f; u32 u; } v; v.f = f;
  u32 r = v.u + 0x7fffu + ((v.u >> 16) & 1u);
  return (u16)(r >> 16);
}

__device__ __forceinline__ u32 pack2bf(float a, float b) {
  union { float f; u32 u; } x, y; x.f = a; y.f = b;
  u32 ua = x.u + 0x7fffu + ((x.u >> 16) & 1u);
  u32 ub = y.u + 0x7fffu + ((y.u >> 16) & 1u);
  return __builtin_amdgcn_perm(ub, ua, 0x07060302u);
}

// compiler emits v_cvt_pk_bf16_f32 pairs
__device__ __forceinline__ s16x4 pk4bf(float a, float b, float c, float d) {
  union { bf16x4 bv; s16x4 sv; } u;
  u.bv[0] = (__bf16)a; u.bv[1] = (__bf16)b; u.bv[2] = (__bf16)c; u.bv[3] = (__bf16)d;
  return u.sv;
}

#if __has_builtin(__builtin_amdgcn_exp2f)
#define EXP2(x) __builtin_amdgcn_exp2f(x)
#else
#define EXP2(x) exp2f(x)
#endif

#if __has_builtin(__builtin_amdgcn_mfma_f32_16x16x16bf16_1k)
__device__ __forceinline__ f32x4 mfma16(s16x4 a, s16x4 b, f32x4 c) {
  return __builtin_amdgcn_mfma_f32_16x16x16bf16_1k(a, b, c, 0, 0, 0);
}
#else
__device__ __forceinline__ f32x4 mfma16(s16x4 a, s16x4 b, f32x4 c) {
  f32x4 d;
  asm volatile("v_mfma_f32_16x16x16_bf16 %0, %1, %2, %3\n\ts_nop 7\n\ts_nop 7"
               : "=v"(d) : "v"(a), "v"(b), "v"(c));
  return d;
}
#endif

// async global->LDS, 16B per lane (CK-style address-space casts)
typedef const __attribute__((address_space(1))) u32 glb_u32;
typedef __attribute__((address_space(3))) u32 lds_u32;
__device__ __forceinline__ void gload16(const u16* g, u16* l) {
  __builtin_amdgcn_global_load_lds((glb_u32*)(const void*)g, (lds_u32*)(void*)l, 16, 0, 0);
}

// ---------------- fused 4x weight transpose + fp32->bf16 ----------------
__global__ __launch_bounds__(256) void transpose_all(const float* __restrict__ Wq,
                                                     const float* __restrict__ Wk,
                                                     const float* __restrict__ Wv,
                                                     const float* __restrict__ Wo,
                                                     u16* __restrict__ Wt) {
  __shared__ u16 t[32][33];
  const float* W = blockIdx.z == 0 ? Wq : blockIdx.z == 1 ? Wk : blockIdx.z == 2 ? Wv : Wo;
  u16* o = Wt + (size_t)blockIdx.z * DMOD * DMOD;
  int bx = blockIdx.x * 32, by = blockIdx.y * 32;
  int x = threadIdx.x, y = threadIdx.y;
  #pragma unroll
  for (int i = 0; i < 32; i += 8)
    t[y + i][x] = f2bf(W[(size_t)(by + y + i) * DMOD + bx + x]);
  __syncthreads();
  #pragma unroll
  for (int i = 0; i < 32; i += 8)
    o[(size_t)(bx + y + i) * DMOD + by + x] = t[x][y + i];
}

// ---------------- x fp32 -> bf16 ----------------
__global__ __launch_bounds__(256) void convert_x(const float* __restrict__ x,
                                                 u16* __restrict__ xb) {
  size_t i = ((size_t)blockIdx.x * 256 + threadIdx.x) * 8;
  float4 f0 = *(const float4*)(x + i);
  float4 f1 = *(const float4*)(x + i + 4);
  uint4 o;
  o.x = pack2bf(f0.x, f0.y); o.y = pack2bf(f0.z, f0.w);
  o.z = pack2bf(f1.x, f1.y); o.w = pack2bf(f1.z, f1.w);
  *(uint4*)(xb + i) = o;
}

// -------- QKV GEMM: [4096x1024]*[3072x1024]^T, m97-style global_load_lds staging --------
// Linear (unpadded) LDS [128][32] required: gload_lds writes wave-uniform base + lane*16.
// 2 barriers/iter, no reg prefetch; 768 blocks = 3/CU exactly -> cross-block overlap
// hides the staging drain (m97: 874 TF with this structure at 128^2/BK=32).
__global__ __launch_bounds__(256, 3) void gemm_qkv(const u16* __restrict__ A,
                                                   const u16* __restrict__ Bt,
                                                   u16* __restrict__ Qo,
                                                   u16* __restrict__ Ko,
                                                   u16* __restrict__ Vo) {
  __shared__ __align__(16) u16 As[128 * 32];
  __shared__ __align__(16) u16 Bs[128 * 32];
  const int tid  = threadIdx.x;
  const int lane = tid & 63, wv = tid >> 6;
  const int wm   = wv >> 1, wn = wv & 1;
  const int lrow = lane & 15, quad = lane >> 4;
  const int tileM = blockIdx.x * 128, tileN = blockIdx.y * 128;

  const f32x4 fz = {0.f, 0.f, 0.f, 0.f};
  f32x4 acc[4][4];
  #pragma unroll
  for (int i = 0; i < 4; ++i)
    #pragma unroll
    for (int j = 0; j < 4; ++j) acc[i][j] = fz;

  for (int kt = 0; kt < DMOD; kt += 32) {
    if (kt) __syncthreads();           // previous compute done reading LDS
    #pragma unroll
    for (int i = 0; i < 2; ++i) {
      int idx = i * 256 + tid;         // 512 chunks of 16B = 128 rows x 64B
      gload16(&A [(size_t)(tileM + (idx >> 2)) * DMOD + kt + (idx & 3) * 8], &As[idx * 8]);
      gload16(&Bt[(size_t)(tileN + (idx >> 2)) * DMOD + kt + (idx & 3) * 8], &Bs[idx * 8]);
    }
    __syncthreads();                   // barrier drains vmcnt -> tile visible

    bf16x8 af[4], bfr[4];
    #pragma unroll
    for (int mt = 0; mt < 4; ++mt)
      af[mt] = *(const bf16x8*)(&As[(wm * 64 + mt * 16 + lrow) * 32 + quad * 8]);
    #pragma unroll
    for (int nt = 0; nt < 4; ++nt)
      bfr[nt] = *(const bf16x8*)(&Bs[(wn * 64 + nt * 16 + lrow) * 32 + quad * 8]);
    #pragma unroll
    for (int mt = 0; mt < 4; ++mt)
      #pragma unroll
      for (int nt = 0; nt < 4; ++nt)
        acc[mt][nt] = __builtin_amdgcn_mfma_f32_16x16x32_bf16(af[mt], bfr[nt],
                                                              acc[mt][nt], 0, 0, 0);
  }

  #pragma unroll
  for (int mt = 0; mt < 4; ++mt) {
    #pragma unroll
    for (int nt = 0; nt < 4; ++nt) {
      int gm0 = tileM + wm * 64 + mt * 16 + quad * 4;
      int gn  = tileN + wn * 64 + nt * 16 + lrow;
      int which = gn >> 10, col = gn & 1023;
      int bb = gm0 >> 11, srw0 = gm0 & (SEQ - 1);
      int hh = col >> 6, dki = col & (DKH - 1);
      size_t bhi = (size_t)(bb * NH + hh);
      if (which == 0) {
        #pragma unroll
        for (int r = 0; r < 4; ++r)
          Qo[(bhi * SEQ + srw0 + r) * DKH + dki] = f2bf(acc[mt][nt][r] * QSCALE);
      } else if (which == 1) {
        #pragma unroll
        for (int r = 0; r < 4; ++r)
          Ko[(bhi * SEQ + srw0 + r) * DKH + dki] = f2bf(acc[mt][nt][r]);
      } else {
        uint2 pk;
        pk.x = pack2bf(acc[mt][nt][0], acc[mt][nt][1]);
        pk.y = pack2bf(acc[mt][nt][2], acc[mt][nt][3]);
        *(uint2*)(&Vo[(((bhi * (SEQ / 4)) + (srw0 >> 2)) * DKH + dki) * 4]) = pk;
      }
    }
  }
}

// -------- out GEMM: [4096x1024]*[1024x1024]^T -> fp32, 128x64, global_load_lds --------
__global__ __launch_bounds__(256, 3) void gemm_out(const u16* __restrict__ A,
                                                   const u16* __restrict__ Bt,
                                                   float* __restrict__ Co) {
  __shared__ __align__(16) u16 As[128 * 32];
  __shared__ __align__(16) u16 Bs[64 * 32];
  const int tid  = threadIdx.x;
  const int lane = tid & 63, wv = tid >> 6;
  const int wm   = wv & 1, wn = wv >> 1;
  const int lrow = lane & 15, quad = lane >> 4;
  const int tileM = blockIdx.x * 128, tileN = blockIdx.y * 64;

  const f32x4 fz = {0.f, 0.f, 0.f, 0.f};
  f32x4 acc[4][2];
  #pragma unroll
  for (int i = 0; i < 4; ++i) { acc[i][0] = fz; acc[i][1] = fz; }

  for (int kt = 0; kt < DMOD; kt += 32) {
    if (kt) __syncthreads();
    #pragma unroll
    for (int i = 0; i < 2; ++i) {
      int idx = i * 256 + tid;
      gload16(&A[(size_t)(tileM + (idx >> 2)) * DMOD + kt + (idx & 3) * 8], &As[idx * 8]);
    }
    gload16(&Bt[(size_t)(tileN + (tid >> 2)) * DMOD + kt + (tid & 3) * 8], &Bs[tid * 8]);
    __syncthreads();

    bf16x8 af[4], bfr[2];
    #pragma unroll
    for (int mt = 0; mt < 4; ++mt)
      af[mt] = *(const bf16x8*)(&As[(wm * 64 + mt * 16 + lrow) * 32 + quad * 8]);
    #pragma unroll
    for (int nt = 0; nt < 2; ++nt)
      bfr[nt] = *(const bf16x8*)(&Bs[(wn * 32 + nt * 16 + lrow) * 32 + quad * 8]);
    #pragma unroll
    for (int mt = 0; mt < 4; ++mt)
      #pragma unroll
      for (int nt = 0; nt < 2; ++nt)
        acc[mt][nt] = __builtin_amdgcn_mfma_f32_16x16x32_bf16(af[mt], bfr[nt],
                                                              acc[mt][nt], 0, 0, 0);
  }

  #pragma unroll
  for (int mt = 0; mt < 4; ++mt)
    #pragma unroll
    for (int nt = 0; nt < 2; ++nt)
      #pragma unroll
      for (int r = 0; r < 4; ++r) {
        int gm = tileM + wm * 64 + mt * 16 + quad * 4 + r;
        int gn = tileN + wn * 32 + nt * 16 + lrow;
        Co[(size_t)gm * DMOD + gn] = acc[mt][nt][r];
      }
}

// ---------------- causal flash attention: S^T form (round-1 structure) ----------------
// 256-thread blocks (4 waves), each wave owns 32 q-rows (two 16-row strips sharing
// every K/V LDS read). Double-buffered K/V, 70 KB -> 2 blocks/CU. Grid (32 bh, 16 t);
// qt = t<8 ? t : 23-t (dispatch-paired blocks carry {p,15-p}).
// Round-4 deltas ONLY: (a) O staged through LDS (reuse KsA) -> full 128B-row uint4
// writes (round-1's direct 8B stores: WRITE 23MB vs 8MB ideal); (b) s_setprio around
// the compute body (T5, +4-7% on phase-diverse attn blocks); (c) v_cvt_pk packing.
#define KP 72
#define VP 132
#define OP 68

__global__ __launch_bounds__(256, 2) void attn_k(const u16* __restrict__ Q,
                                                 const u16* __restrict__ Kg,
                                                 const u16* __restrict__ Vg,
                                                 u16* __restrict__ Og) {
  __shared__ __align__(16) u16 KsA[128 * KP];
  __shared__ __align__(16) u16 VsA[64 * VP];
  __shared__ __align__(16) u16 KsB[128 * KP];
  __shared__ __align__(16) u16 VsB[64 * VP];

  const int tid  = threadIdx.x;
  const int lane = tid & 63, w = tid >> 6;          // w in 0..3
  const int lrow = lane & 15, quad = lane >> 4;
  const int bh = blockIdx.x;
  const int t  = blockIdx.y;
  const int qt = (t < 8) ? t : 23 - t;              // balanced pairing map
  const int b = bh >> 4, h = bh & 15;

  const u16* Qbh = Q  + (size_t)bh * SEQ * DKH;
  const u16* Kbh = Kg + (size_t)bh * SEQ * DKH;
  const u16* Vbh = Vg + (size_t)bh * SEQ * DKH;     // [s/4][dk][4]

  const int jmax = qt;

  // Q fragments for the wave's two strips (rows qt*128 + (2w+s)*16 + lrow)
  bf16x8 bq[2][2];
  #pragma unroll
  for (int s = 0; s < 2; ++s)
    #pragma unroll
    for (int kk = 0; kk < 2; ++kk)
      bq[s][kk] = *(const bf16x8*)(&Qbh[(size_t)(qt * 128 + (2 * w + s) * 16 + lrow) * DKH
                                        + kk * 32 + quad * 8]);

  // staging: 256 threads x 4 chunks of 16B cover the 16KB K tile / 16KB V tile
  uint4 kreg[4], vreg[4];
  #pragma unroll
  for (int k = 0; k < 4; ++k) {
    int ci = k * 256 + tid;
    kreg[k] = *(const uint4*)(&Kbh[(size_t)(ci >> 3) * DKH + (ci & 7) * 8]);
    vreg[k] = *(const uint4*)(&Vbh[(size_t)(ci >> 5) * 256 + (ci & 31) * 8]);
  }

  const f32x4 fz = {0.f, 0.f, 0.f, 0.f};
  f32x4 oacc[2][4];
  #pragma unroll
  for (int s = 0; s < 2; ++s)
    #pragma unroll
    for (int d = 0; d < 4; ++d) oacc[s][d] = fz;
  float lsum[2] = {0.f, 0.f};

  int cur = 0;
  for (int j = 0; j <= jmax; ++j) {
    u16* Ks = cur ? KsB : KsA;
    u16* Vs = cur ? VsB : VsA;

    #pragma unroll
    for (int k = 0; k < 4; ++k) {
      int ci = k * 256 + tid;
      *(uint4*)(&Ks[(ci >> 3) * KP + (ci & 7) * 8]) = kreg[k];
      int sq = ci >> 5, dkp = ci & 31;
      union { uint4 q; uint2 d[2]; } vv; vv.q = vreg[k];
      *(uint2*)(&Vs[(2 * dkp)     * VP + 4 * sq]) = vv.d[0];
      *(uint2*)(&Vs[(2 * dkp + 1) * VP + 4 * sq]) = vv.d[1];
    }

    if (j < jmax) {
      const int jn = j + 1;
      #pragma unroll
      for (int k = 0; k < 4; ++k) {
        int ci = k * 256 + tid;
        kreg[k] = *(const uint4*)(&Kbh[(size_t)(jn * 128 + (ci >> 3)) * DKH + (ci & 7) * 8]);
        vreg[k] = *(const uint4*)(&Vbh[(size_t)(jn * 32 + (ci >> 5)) * 256 + (ci & 31) * 8]);
      }
    }

    __syncthreads();

    if (j < jmax) {
      __builtin_amdgcn_s_setprio(1);
      // full k-tile for both strips; every ak/av LDS read feeds 2 MFMAs
      f32x4 sacc[2][8];
      #pragma unroll
      for (int s = 0; s < 2; ++s)
        #pragma unroll
        for (int m = 0; m < 8; ++m) sacc[s][m] = fz;
      #pragma unroll
      for (int kk = 0; kk < 2; ++kk)
        #pragma unroll
        for (int m = 0; m < 8; ++m) {
          bf16x8 ak = *(const bf16x8*)(&Ks[(m * 16 + lrow) * KP + kk * 32 + quad * 8]);
          sacc[0][m] = __builtin_amdgcn_mfma_f32_16x16x32_bf16(ak, bq[0][kk], sacc[0][m], 0, 0, 0);
          sacc[1][m] = __builtin_amdgcn_mfma_f32_16x16x32_bf16(ak, bq[1][kk], sacc[1][m], 0, 0, 0);
        }
      #pragma unroll
      for (int m = 0; m < 8; ++m) {
        float p00 = EXP2(sacc[0][m][0]), p01 = EXP2(sacc[0][m][1]);
        float p02 = EXP2(sacc[0][m][2]), p03 = EXP2(sacc[0][m][3]);
        float p10 = EXP2(sacc[1][m][0]), p11 = EXP2(sacc[1][m][1]);
        float p12 = EXP2(sacc[1][m][2]), p13 = EXP2(sacc[1][m][3]);
        lsum[0] += (p00 + p01) + (p02 + p03);
        lsum[1] += (p10 + p11) + (p12 + p13);
        s16x4 pk0 = pk4bf(p00, p01, p02, p03);
        s16x4 pk1 = pk4bf(p10, p11, p12, p13);
        #pragma unroll
        for (int d = 0; d < 4; ++d) {
          s16x4 av = *(const s16x4*)(&Vs[(d * 16 + lrow) * VP + m * 16 + quad * 4]);
          oacc[0][d] = mfma16(av, pk0, oacc[0][d]);
          oacc[1][d] = mfma16(av, pk1, oacc[1][d]);
        }
      }
      __builtin_amdgcn_s_setprio(0);
    } else {
      // diagonal k-tile: per-strip triangular handling
      #pragma unroll
      for (int s = 0; s < 2; ++s) {
        const int ss = 2 * w + s;
        for (int m = 0; m < ss; ++m) {
          f32x4 sv = fz;
          #pragma unroll
          for (int kk = 0; kk < 2; ++kk) {
            bf16x8 ak = *(const bf16x8*)(&Ks[(m * 16 + lrow) * KP + kk * 32 + quad * 8]);
            sv = __builtin_amdgcn_mfma_f32_16x16x32_bf16(ak, bq[s][kk], sv, 0, 0, 0);
          }
          float p0 = EXP2(sv[0]), p1 = EXP2(sv[1]), p2 = EXP2(sv[2]), p3 = EXP2(sv[3]);
          lsum[s] += (p0 + p1) + (p2 + p3);
          s16x4 pk = pk4bf(p0, p1, p2, p3);
          #pragma unroll
          for (int d = 0; d < 4; ++d) {
            s16x4 av = *(const s16x4*)(&Vs[(d * 16 + lrow) * VP + m * 16 + quad * 4]);
            oacc[s][d] = mfma16(av, pk, oacc[s][d]);
          }
        }
        { // m == ss : masked diagonal strip (k > q -> 0)
          f32x4 sv = fz;
          #pragma unroll
          for (int kk = 0; kk < 2; ++kk) {
            bf16x8 ak = *(const bf16x8*)(&Ks[(ss * 16 + lrow) * KP + kk * 32 + quad * 8]);
            sv = __builtin_amdgcn_mfma_f32_16x16x32_bf16(ak, bq[s][kk], sv, 0, 0, 0);
          }
          float p[4];
          #pragma unroll
          for (int r = 0; r < 4; ++r)
            p[r] = (quad * 4 + r > lrow) ? 0.f : EXP2(sv[r]);
          lsum[s] += (p[0] + p[1]) + (p[2] + p[3]);
          s16x4 pk = pk4bf(p[0], p[1], p[2], p[3]);
          #pragma unroll
          for (int d = 0; d < 4; ++d) {
            s16x4 av = *(const s16x4*)(&Vs[(d * 16 + lrow) * VP + ss * 16 + quad * 4]);
            oacc[s][d] = mfma16(av, pk, oacc[s][d]);
          }
        }
      }
    }
    cur ^= 1;
  }

  // normalize; stage O rows in LDS (reuse KsA); write full 128B rows coalesced
  float inv[2];
  #pragma unroll
  for (int s = 0; s < 2; ++s) {
    float v = lsum[s];
    v += __shfl_xor(v, 16, 64);
    v += __shfl_xor(v, 32, 64);
    inv[s] = 1.f / v;
  }

  __syncthreads();                     // all waves done reading K/V buffers
  u16* Osr = KsA;                      // 128 rows x OP (17.4KB <= 18.4KB)
  #pragma unroll
  for (int s = 0; s < 2; ++s) {
    int row = (2 * w + s) * 16 + lrow;
    #pragma unroll
    for (int d = 0; d < 4; ++d) {
      uint2 pkk;
      pkk.x = pack2bf(oacc[s][d][0] * inv[s], oacc[s][d][1] * inv[s]);
      pkk.y = pack2bf(oacc[s][d][2] * inv[s], oacc[s][d][3] * inv[s]);
      *(uint2*)(&Osr[row * OP + d * 16 + quad * 4]) = pkk;
    }
  }
  __syncthreads();
  #pragma unroll
  for (int k = 0; k < 4; ++k) {
    int c = k * 256 + tid;             // 1024 chunks of 16B = 128 rows x 128B
    int row = c >> 3, ch = c & 7;
    uint4 v = *(const uint4*)(&Osr[row * OP + ch * 8]);
    *(uint4*)(&Og[(size_t)(b * SEQ + qt * 128 + row) * DMOD + h * DKH + ch * 8]) = v;
  }
}

// ---------------- launch ----------------
extern "C" void kernel_launch(void* const* d_in, const int* in_sizes, int n_in,
                              void* d_out, int out_size, void* d_ws, size_t ws_size,
                              hipStream_t stream) {
  const float* x  = (const float*)d_in[0];
  const float* Wq = (const float*)d_in[1];
  const float* Wk = (const float*)d_in[2];
  const float* Wv = (const float*)d_in[3];
  const float* Wo = (const float*)d_in[4];

  u16* ws = (u16*)d_ws;
  const size_t WSZ = (size_t)DMOD * DMOD;
  const size_t TSZ = (size_t)BAT * NH * SEQ * DKH;
  u16* Wt  = ws;                 // 4 transposed weights
  u16* Wto = Wt + 3 * WSZ;
  u16* xb  = Wt + 4 * WSZ;       // x bf16; dead after QKV -> reused as Ob
  u16* Qb  = xb + TSZ;
  u16* Kb  = Qb + TSZ;
  u16* Vb  = Kb + TSZ;           // [b,h,s/4,dk,4]
  u16* Ob  = xb;

  transpose_all<<<dim3(32, 32, 4), dim3(32, 8), 0, stream>>>(Wq, Wk, Wv, Wo, Wt);
  convert_x<<<dim3(2048), 256, 0, stream>>>(x, xb);

  gemm_qkv<<<dim3(32, 24), 256, 0, stream>>>(xb, Wt, Qb, Kb, Vb);

  attn_k<<<dim3(32, 16), 256, 0, stream>>>(Qb, Kb, Vb, Ob);

  gemm_out<<<dim3(32, 16), 256, 0, stream>>>(Ob, Wto, (float*)d_out);
}

// Round 5
// 178.424 us; speedup vs baseline: 1.6130x; 1.0153x over previous
//
#include <hip/hip_runtime.h>

typedef unsigned short u16;
typedef unsigned int   u32;

using bf16x8 = __attribute__((ext_vector_type(8))) __bf16;
using bf16x4 = __attribute__((ext_vector_type(4))) __bf16;
using f32x4  = __attribute__((ext_vector_type(4))) float;
using s16x4  = __attribute__((ext_vector_type(4))) short;

#define NH    16
#define DKH   64
#define SEQ   2048
#define BAT   2
#define DMOD  1024

// 0.125 (1/sqrt(dk)) * log2(e): scores in log2 domain -> p = exp2(s)
#define QSCALE 0.18033688011112042f

__device__ __forceinline__ u16 f2bf(float f) {
  union { float f; u32 u; } v; v.f = f;
  u32 r = v.u + 0x7fffu + ((v.u >> 16) & 1u);
  return (u16)(r >> 16);
}

__device__ __forceinline__ u32 pack2bf(float a, float b) {
  union { float f; u32 u; } x, y; x.f = a; y.f = b;
  u32 ua = x.u + 0x7fffu + ((x.u >> 16) & 1u);
  u32 ub = y.u + 0x7fffu + ((y.u >> 16) & 1u);
  return __builtin_amdgcn_perm(ub, ua, 0x07060302u);
}

// compiler emits v_cvt_pk_bf16_f32 pairs
__device__ __forceinline__ s16x4 pk4bf(float a, float b, float c, float d) {
  union { bf16x4 bv; s16x4 sv; } u;
  u.bv[0] = (__bf16)a; u.bv[1] = (__bf16)b; u.bv[2] = (__bf16)c; u.bv[3] = (__bf16)d;
  return u.sv;
}

#if __has_builtin(__builtin_amdgcn_exp2f)
#define EXP2(x) __builtin_amdgcn_exp2f(x)
#else
#define EXP2(x) exp2f(x)
#endif

#if __has_builtin(__builtin_amdgcn_mfma_f32_16x16x16bf16_1k)
__device__ __forceinline__ f32x4 mfma16(s16x4 a, s16x4 b, f32x4 c) {
  return __builtin_amdgcn_mfma_f32_16x16x16bf16_1k(a, b, c, 0, 0, 0);
}
#else
__device__ __forceinline__ f32x4 mfma16(s16x4 a, s16x4 b, f32x4 c) {
  f32x4 d;
  asm volatile("v_mfma_f32_16x16x16_bf16 %0, %1, %2, %3\n\ts_nop 7\n\ts_nop 7"
               : "=v"(d) : "v"(a), "v"(b), "v"(c));
  return d;
}
#endif

// async global->LDS, 16B per lane. Dest must be linear in tid within each wave
// (HW uses wave-uniform base + lane*16; first-lane pointer is the base).
typedef const __attribute__((address_space(1))) u32 glb_u32;
typedef __attribute__((address_space(3))) u32 lds_u32;
__device__ __forceinline__ void gload16(const u16* g, u16* l) {
  __builtin_amdgcn_global_load_lds((glb_u32*)(const void*)g, (lds_u32*)(void*)l, 16, 0, 0);
}

// ---------------- fused 4x weight transpose + fp32->bf16 ----------------
__global__ __launch_bounds__(256) void transpose_all(const float* __restrict__ Wq,
                                                     const float* __restrict__ Wk,
                                                     const float* __restrict__ Wv,
                                                     const float* __restrict__ Wo,
                                                     u16* __restrict__ Wt) {
  __shared__ u16 t[32][33];
  const float* W = blockIdx.z == 0 ? Wq : blockIdx.z == 1 ? Wk : blockIdx.z == 2 ? Wv : Wo;
  u16* o = Wt + (size_t)blockIdx.z * DMOD * DMOD;
  int bx = blockIdx.x * 32, by = blockIdx.y * 32;
  int x = threadIdx.x, y = threadIdx.y;
  #pragma unroll
  for (int i = 0; i < 32; i += 8)
    t[y + i][x] = f2bf(W[(size_t)(by + y + i) * DMOD + bx + x]);
  __syncthreads();
  #pragma unroll
  for (int i = 0; i < 32; i += 8)
    o[(size_t)(bx + y + i) * DMOD + by + x] = t[x][y + i];
}

// ---------------- x fp32 -> bf16 ----------------
__global__ __launch_bounds__(256) void convert_x(const float* __restrict__ x,
                                                 u16* __restrict__ xb) {
  size_t i = ((size_t)blockIdx.x * 256 + threadIdx.x) * 8;
  float4 f0 = *(const float4*)(x + i);
  float4 f1 = *(const float4*)(x + i + 4);
  uint4 o;
  o.x = pack2bf(f0.x, f0.y); o.y = pack2bf(f0.z, f0.w);
  o.z = pack2bf(f1.x, f1.y); o.w = pack2bf(f1.z, f1.w);
  *(uint4*)(xb + i) = o;
}

// -------- QKV GEMM: [4096x1024]*[3072x1024]^T, m97-style global_load_lds staging --------
__global__ __launch_bounds__(256, 3) void gemm_qkv(const u16* __restrict__ A,
                                                   const u16* __restrict__ Bt,
                                                   u16* __restrict__ Qo,
                                                   u16* __restrict__ Ko,
                                                   u16* __restrict__ Vo) {
  __shared__ __align__(16) u16 As[128 * 32];
  __shared__ __align__(16) u16 Bs[128 * 32];
  const int tid  = threadIdx.x;
  const int lane = tid & 63, wv = tid >> 6;
  const int wm   = wv >> 1, wn = wv & 1;
  const int lrow = lane & 15, quad = lane >> 4;
  const int tileM = blockIdx.x * 128, tileN = blockIdx.y * 128;

  const f32x4 fz = {0.f, 0.f, 0.f, 0.f};
  f32x4 acc[4][4];
  #pragma unroll
  for (int i = 0; i < 4; ++i)
    #pragma unroll
    for (int j = 0; j < 4; ++j) acc[i][j] = fz;

  for (int kt = 0; kt < DMOD; kt += 32) {
    if (kt) __syncthreads();           // previous compute done reading LDS
    #pragma unroll
    for (int i = 0; i < 2; ++i) {
      int idx = i * 256 + tid;         // 512 chunks of 16B = 128 rows x 64B
      gload16(&A [(size_t)(tileM + (idx >> 2)) * DMOD + kt + (idx & 3) * 8], &As[idx * 8]);
      gload16(&Bt[(size_t)(tileN + (idx >> 2)) * DMOD + kt + (idx & 3) * 8], &Bs[idx * 8]);
    }
    __syncthreads();                   // barrier drains vmcnt -> tile visible

    bf16x8 af[4], bfr[4];
    #pragma unroll
    for (int mt = 0; mt < 4; ++mt)
      af[mt] = *(const bf16x8*)(&As[(wm * 64 + mt * 16 + lrow) * 32 + quad * 8]);
    #pragma unroll
    for (int nt = 0; nt < 4; ++nt)
      bfr[nt] = *(const bf16x8*)(&Bs[(wn * 64 + nt * 16 + lrow) * 32 + quad * 8]);
    #pragma unroll
    for (int mt = 0; mt < 4; ++mt)
      #pragma unroll
      for (int nt = 0; nt < 4; ++nt)
        acc[mt][nt] = __builtin_amdgcn_mfma_f32_16x16x32_bf16(af[mt], bfr[nt],
                                                              acc[mt][nt], 0, 0, 0);
  }

  #pragma unroll
  for (int mt = 0; mt < 4; ++mt) {
    #pragma unroll
    for (int nt = 0; nt < 4; ++nt) {
      int gm0 = tileM + wm * 64 + mt * 16 + quad * 4;
      int gn  = tileN + wn * 64 + nt * 16 + lrow;
      int which = gn >> 10, col = gn & 1023;
      int bb = gm0 >> 11, srw0 = gm0 & (SEQ - 1);
      int hh = col >> 6, dki = col & (DKH - 1);
      size_t bhi = (size_t)(bb * NH + hh);
      if (which == 0) {
        #pragma unroll
        for (int r = 0; r < 4; ++r)
          Qo[(bhi * SEQ + srw0 + r) * DKH + dki] = f2bf(acc[mt][nt][r] * QSCALE);
      } else if (which == 1) {
        #pragma unroll
        for (int r = 0; r < 4; ++r)
          Ko[(bhi * SEQ + srw0 + r) * DKH + dki] = f2bf(acc[mt][nt][r]);
      } else {
        uint2 pk;
        pk.x = pack2bf(acc[mt][nt][0], acc[mt][nt][1]);
        pk.y = pack2bf(acc[mt][nt][2], acc[mt][nt][3]);
        *(uint2*)(&Vo[(((bhi * (SEQ / 4)) + (srw0 >> 2)) * DKH + dki) * 4]) = pk;
      }
    }
  }
}

// -------- out GEMM: [4096x1024]*[1024x1024]^T -> fp32, 128x64, global_load_lds --------
__global__ __launch_bounds__(256, 3) void gemm_out(const u16* __restrict__ A,
                                                   const u16* __restrict__ Bt,
                                                   float* __restrict__ Co) {
  __shared__ __align__(16) u16 As[128 * 32];
  __shared__ __align__(16) u16 Bs[64 * 32];
  const int tid  = threadIdx.x;
  const int lane = tid & 63, wv = tid >> 6;
  const int wm   = wv & 1, wn = wv >> 1;
  const int lrow = lane & 15, quad = lane >> 4;
  const int tileM = blockIdx.x * 128, tileN = blockIdx.y * 64;

  const f32x4 fz = {0.f, 0.f, 0.f, 0.f};
  f32x4 acc[4][2];
  #pragma unroll
  for (int i = 0; i < 4; ++i) { acc[i][0] = fz; acc[i][1] = fz; }

  for (int kt = 0; kt < DMOD; kt += 32) {
    if (kt) __syncthreads();
    #pragma unroll
    for (int i = 0; i < 2; ++i) {
      int idx = i * 256 + tid;
      gload16(&A[(size_t)(tileM + (idx >> 2)) * DMOD + kt + (idx & 3) * 8], &As[idx * 8]);
    }
    gload16(&Bt[(size_t)(tileN + (tid >> 2)) * DMOD + kt + (tid & 3) * 8], &Bs[tid * 8]);
    __syncthreads();

    bf16x8 af[4], bfr[2];
    #pragma unroll
    for (int mt = 0; mt < 4; ++mt)
      af[mt] = *(const bf16x8*)(&As[(wm * 64 + mt * 16 + lrow) * 32 + quad * 8]);
    #pragma unroll
    for (int nt = 0; nt < 2; ++nt)
      bfr[nt] = *(const bf16x8*)(&Bs[(wn * 32 + nt * 16 + lrow) * 32 + quad * 8]);
    #pragma unroll
    for (int mt = 0; mt < 4; ++mt)
      #pragma unroll
      for (int nt = 0; nt < 2; ++nt)
        acc[mt][nt] = __builtin_amdgcn_mfma_f32_16x16x32_bf16(af[mt], bfr[nt],
                                                              acc[mt][nt], 0, 0, 0);
  }

  #pragma unroll
  for (int mt = 0; mt < 4; ++mt)
    #pragma unroll
    for (int nt = 0; nt < 2; ++nt)
      #pragma unroll
      for (int r = 0; r < 4; ++r) {
        int gm = tileM + wm * 64 + mt * 16 + quad * 4 + r;
        int gn = tileN + wn * 32 + nt * 16 + lrow;
        Co[(size_t)gm * DMOD + gn] = acc[mt][nt][r];
      }
}

// ---------------- causal flash attention: S^T form, small-block gload staging ----------------
// Round-5: 128-thread blocks (2 waves x 32 q-rows = 64-row q-tile); K/V staged by
// global_load_lds into SINGLE-buffered linear [128][64] tiles (32 KB -> 4-5 blocks/CU).
// 16B-chunk XOR swizzle (chunk ^= row&7) applied to the per-lane GLOBAL source and the
// LDS read address (both-sides, linear dest). Zero staging registers -> no round-2 spill.
// Grid (32 bh, 32 y), qb = (y+bh)&31: co-resident sets mix lengths {q,q+8,q+16,q+24},
// so concurrency survives short-block retirement (round-1/4 defect: occupancy 12%).
// Single-buffer issue->drain gap is covered by sibling blocks (m97 mechanism).
#define OP 68

__global__ __launch_bounds__(128, 2) void attn_k(const u16* __restrict__ Q,
                                                 const u16* __restrict__ Kg,
                                                 const u16* __restrict__ Vg,
                                                 u16* __restrict__ Og) {
  __shared__ __align__(16) u16 Ks[128 * 64];   // K tile: [k-row 0..127][dk 0..63], swizzled
  __shared__ __align__(16) u16 Vs[32 * 256];   // V tile: global layout [sq][dk][4], swizzled

  const int tid  = threadIdx.x;
  const int lane = tid & 63, w = tid >> 6;          // w in 0..1
  const int lrow = lane & 15, quad = lane >> 4;
  const int bh = blockIdx.x;
  const int qb = (int)((blockIdx.y + bh) & 31);     // 64-row q-block, decorrelated from id
  const int b = bh >> 4, h = bh & 15;
  const int jmax = qb >> 1;                          // 128-wide k-tiles
  const int qoff = qb & 1;                           // which half of diag tile

  const u16* Qbh = Q  + (size_t)bh * SEQ * DKH;
  const u16* Kbh = Kg + (size_t)bh * SEQ * DKH;
  const u16* Vbh = Vg + (size_t)bh * SEQ * DKH;     // [s/4][dk][4]

  // Q fragments for the wave's two strips (q-rows qb*64 + (2w+s)*16 + lrow)
  bf16x8 bq[2][2];
  #pragma unroll
  for (int s = 0; s < 2; ++s)
    #pragma unroll
    for (int kk = 0; kk < 2; ++kk)
      bq[s][kk] = *(const bf16x8*)(&Qbh[(size_t)(qb * 64 + (2 * w + s) * 16 + lrow) * DKH
                                        + kk * 32 + quad * 8]);

  const f32x4 fz = {0.f, 0.f, 0.f, 0.f};
  f32x4 oacc[2][4];
  #pragma unroll
  for (int s = 0; s < 2; ++s)
    #pragma unroll
    for (int d = 0; d < 4; ++d) oacc[s][d] = fz;
  float lsum[2] = {0.f, 0.f};

  for (int j = 0; j <= jmax; ++j) {
    if (j) __syncthreads();            // previous compute done reading LDS

    // stage K tile: 1024 chunks of 16B; dest linear in tid, source inverse-swizzled
    #pragma unroll
    for (int i = 0; i < 8; ++i) {
      int cD = i * 128 + tid;
      int r = cD >> 3, c = cD & 7;
      gload16(&Kbh[(size_t)(j * 128 + r) * DKH + ((c ^ (r & 7)) << 3)], &Ks[cD * 8]);
    }
    // stage V tile: [sq][dk][4] rows of 512B = 32 chunks, XOR chunk with sq&7
    #pragma unroll
    for (int i = 0; i < 8; ++i) {
      int cD = i * 128 + tid;
      int sq = cD >> 5, c = cD & 31;
      gload16(&Vbh[(size_t)(j * 32 + sq) * 256 + ((c ^ (sq & 7)) << 3)], &Vs[cD * 8]);
    }

    __syncthreads();                   // drains vmcnt -> tile visible

    if (j < jmax) {
      __builtin_amdgcn_s_setprio(1);
      // full k-tile for both strips; every ak/av LDS read feeds 2 MFMAs
      f32x4 sacc[2][8];
      #pragma unroll
      for (int s = 0; s < 2; ++s)
        #pragma unroll
        for (int m = 0; m < 8; ++m) sacc[s][m] = fz;
      #pragma unroll
      for (int kk = 0; kk < 2; ++kk)
        #pragma unroll
        for (int m = 0; m < 8; ++m) {
          bf16x8 ak = *(const bf16x8*)(&Ks[(m * 16 + lrow) * 64
                                           + (((kk * 4 + quad) ^ (lrow & 7)) << 3)]);
          sacc[0][m] = __builtin_amdgcn_mfma_f32_16x16x32_bf16(ak, bq[0][kk], sacc[0][m], 0, 0, 0);
          sacc[1][m] = __builtin_amdgcn_mfma_f32_16x16x32_bf16(ak, bq[1][kk], sacc[1][m], 0, 0, 0);
        }
      #pragma unroll
      for (int m = 0; m < 8; ++m) {
        float p00 = EXP2(sacc[0][m][0]), p01 = EXP2(sacc[0][m][1]);
        float p02 = EXP2(sacc[0][m][2]), p03 = EXP2(sacc[0][m][3]);
        float p10 = EXP2(sacc[1][m][0]), p11 = EXP2(sacc[1][m][1]);
        float p12 = EXP2(sacc[1][m][2]), p13 = EXP2(sacc[1][m][3]);
        lsum[0] += (p00 + p01) + (p02 + p03);
        lsum[1] += (p10 + p11) + (p12 + p13);
        s16x4 pk0 = pk4bf(p00, p01, p02, p03);
        s16x4 pk1 = pk4bf(p10, p11, p12, p13);
        const int sq = m * 4 + quad;
        #pragma unroll
        for (int d = 0; d < 4; ++d) {
          int dk = d * 16 + lrow;
          s16x4 av = *(const s16x4*)(&Vs[sq * 256
                                         + ((((dk >> 1) ^ (sq & 7)) << 3) | ((dk & 1) << 2))]);
          oacc[0][d] = mfma16(av, pk0, oacc[0][d]);
          oacc[1][d] = mfma16(av, pk1, oacc[1][d]);
        }
      }
      __builtin_amdgcn_s_setprio(0);
    } else {
      // diagonal k-tile: strip local index L = qoff*4 + 2w+s within the 128-row tile
      #pragma unroll
      for (int s = 0; s < 2; ++s) {
        const int L = qoff * 4 + 2 * w + s;
        for (int m = 0; m < L; ++m) {
          f32x4 sv = fz;
          #pragma unroll
          for (int kk = 0; kk < 2; ++kk) {
            bf16x8 ak = *(const bf16x8*)(&Ks[(m * 16 + lrow) * 64
                                             + (((kk * 4 + quad) ^ (lrow & 7)) << 3)]);
            sv = __builtin_amdgcn_mfma_f32_16x16x32_bf16(ak, bq[s][kk], sv, 0, 0, 0);
          }
          float p0 = EXP2(sv[0]), p1 = EXP2(sv[1]), p2 = EXP2(sv[2]), p3 = EXP2(sv[3]);
          lsum[s] += (p0 + p1) + (p2 + p3);
          s16x4 pk = pk4bf(p0, p1, p2, p3);
          const int sq = m * 4 + quad;
          #pragma unroll
          for (int d = 0; d < 4; ++d) {
            int dk = d * 16 + lrow;
            s16x4 av = *(const s16x4*)(&Vs[sq * 256
                                           + ((((dk >> 1) ^ (sq & 7)) << 3) | ((dk & 1) << 2))]);
            oacc[s][d] = mfma16(av, pk, oacc[s][d]);
          }
        }
        { // m == L : masked diagonal strip (k > q -> 0)
          f32x4 sv = fz;
          #pragma unroll
          for (int kk = 0; kk < 2; ++kk) {
            bf16x8 ak = *(const bf16x8*)(&Ks[(L * 16 + lrow) * 64
                                             + (((kk * 4 + quad) ^ (lrow & 7)) << 3)]);
            sv = __builtin_amdgcn_mfma_f32_16x16x32_bf16(ak, bq[s][kk], sv, 0, 0, 0);
          }
          float p[4];
          #pragma unroll
          for (int r = 0; r < 4; ++r)
            p[r] = (quad * 4 + r > lrow) ? 0.f : EXP2(sv[r]);
          lsum[s] += (p[0] + p[1]) + (p[2] + p[3]);
          s16x4 pk = pk4bf(p[0], p[1], p[2], p[3]);
          const int sq = L * 4 + quad;
          #pragma unroll
          for (int d = 0; d < 4; ++d) {
            int dk = d * 16 + lrow;
            s16x4 av = *(const s16x4*)(&Vs[sq * 256
                                           + ((((dk >> 1) ^ (sq & 7)) << 3) | ((dk & 1) << 2))]);
            oacc[s][d] = mfma16(av, pk, oacc[s][d]);
          }
        }
      }
    }
  }

  // normalize; stage O rows in LDS (reuse Ks); write full 128B rows coalesced
  float inv[2];
  #pragma unroll
  for (int s = 0; s < 2; ++s) {
    float v = lsum[s];
    v += __shfl_xor(v, 16, 64);
    v += __shfl_xor(v, 32, 64);
    inv[s] = 1.f / v;
  }

  __syncthreads();                     // all waves done reading K/V
  u16* Osr = Ks;                       // 64 rows x OP (8.7 KB)
  #pragma unroll
  for (int s = 0; s < 2; ++s) {
    int row = (2 * w + s) * 16 + lrow;
    #pragma unroll
    for (int d = 0; d < 4; ++d) {
      uint2 pkk;
      pkk.x = pack2bf(oacc[s][d][0] * inv[s], oacc[s][d][1] * inv[s]);
      pkk.y = pack2bf(oacc[s][d][2] * inv[s], oacc[s][d][3] * inv[s]);
      *(uint2*)(&Osr[row * OP + d * 16 + quad * 4]) = pkk;
    }
  }
  __syncthreads();
  #pragma unroll
  for (int k = 0; k < 4; ++k) {
    int c = k * 128 + tid;             // 512 chunks of 16B = 64 rows x 128B
    int row = c >> 3, ch = c & 7;
    uint4 v = *(const uint4*)(&Osr[row * OP + ch * 8]);
    *(uint4*)(&Og[(size_t)(b * SEQ + qb * 64 + row) * DMOD + h * DKH + ch * 8]) = v;
  }
}

// ---------------- launch ----------------
extern "C" void kernel_launch(void* const* d_in, const int* in_sizes, int n_in,
                              void* d_out, int out_size, void* d_ws, size_t ws_size,
                              hipStream_t stream) {
  const float* x  = (const float*)d_in[0];
  const float* Wq = (const float*)d_in[1];
  const float* Wk = (const float*)d_in[2];
  const float* Wv = (const float*)d_in[3];
  const float* Wo = (const float*)d_in[4];

  u16* ws = (u16*)d_ws;
  const size_t WSZ = (size_t)DMOD * DMOD;
  const size_t TSZ = (size_t)BAT * NH * SEQ * DKH;
  u16* Wt  = ws;                 // 4 transposed weights
  u16* Wto = Wt + 3 * WSZ;
  u16* xb  = Wt + 4 * WSZ;       // x bf16; dead after QKV -> reused as Ob
  u16* Qb  = xb + TSZ;
  u16* Kb  = Qb + TSZ;
  u16* Vb  = Kb + TSZ;           // [b,h,s/4,dk,4]
  u16* Ob  = xb;

  transpose_all<<<dim3(32, 32, 4), dim3(32, 8), 0, stream>>>(Wq, Wk, Wv, Wo, Wt);
  convert_x<<<dim3(2048), 256, 0, stream>>>(x, xb);

  gemm_qkv<<<dim3(32, 24), 256, 0, stream>>>(xb, Wt, Qb, Kb, Vb);

  attn_k<<<dim3(32, 32), 128, 0, stream>>>(Qb, Kb, Vb, Ob);

  gemm_out<<<dim3(32, 16), 256, 0, stream>>>(Ob, Wto, (float*)d_out);
}

// Round 6
// 174.164 us; speedup vs baseline: 1.6524x; 1.0245x over previous
//
#include <hip/hip_runtime.h>

typedef unsigned short u16;
typedef unsigned int   u32;

using bf16x8 = __attribute__((ext_vector_type(8))) __bf16;
using bf16x4 = __attribute__((ext_vector_type(4))) __bf16;
using f32x4  = __attribute__((ext_vector_type(4))) float;
using s16x4  = __attribute__((ext_vector_type(4))) short;

#define NH    16
#define DKH   64
#define SEQ   2048
#define BAT   2
#define DMOD  1024

// 0.125 (1/sqrt(dk)) * log2(e): scores in log2 domain -> p = exp2(s)
#define QSCALE 0.18033688011112042f

__device__ __forceinline__ u16 f2bf(float f) {
  union { float f; u32 u; } v; v.f = f;
  u32 r = v.u + 0x7fffu + ((v.u >> 16) & 1u);
  return (u16)(r >> 16);
}

__device__ __forceinline__ u32 pack2bf(float a, float b) {
  union { float f; u32 u; } x, y; x.f = a; y.f = b;
  u32 ua = x.u + 0x7fffu + ((x.u >> 16) & 1u);
  u32 ub = y.u + 0x7fffu + ((y.u >> 16) & 1u);
  return __builtin_amdgcn_perm(ub, ua, 0x07060302u);
}

// compiler emits v_cvt_pk_bf16_f32 pairs
__device__ __forceinline__ s16x4 pk4bf(float a, float b, float c, float d) {
  union { bf16x4 bv; s16x4 sv; } u;
  u.bv[0] = (__bf16)a; u.bv[1] = (__bf16)b; u.bv[2] = (__bf16)c; u.bv[3] = (__bf16)d;
  return u.sv;
}

#if __has_builtin(__builtin_amdgcn_exp2f)
#define EXP2(x) __builtin_amdgcn_exp2f(x)
#else
#define EXP2(x) exp2f(x)
#endif

#if __has_builtin(__builtin_amdgcn_mfma_f32_16x16x16bf16_1k)
__device__ __forceinline__ f32x4 mfma16(s16x4 a, s16x4 b, f32x4 c) {
  return __builtin_amdgcn_mfma_f32_16x16x16bf16_1k(a, b, c, 0, 0, 0);
}
#else
__device__ __forceinline__ f32x4 mfma16(s16x4 a, s16x4 b, f32x4 c) {
  f32x4 d;
  asm volatile("v_mfma_f32_16x16x16_bf16 %0, %1, %2, %3\n\ts_nop 7\n\ts_nop 7"
               : "=v"(d) : "v"(a), "v"(b), "v"(c));
  return d;
}
#endif

// async global->LDS, 16B per lane. Dest must be linear in tid within each wave
// (HW uses wave-uniform base + lane*16; first-lane pointer is the base).
typedef const __attribute__((address_space(1))) u32 glb_u32;
typedef __attribute__((address_space(3))) u32 lds_u32;
__device__ __forceinline__ void gload16(const u16* g, u16* l) {
  __builtin_amdgcn_global_load_lds((glb_u32*)(const void*)g, (lds_u32*)(void*)l, 16, 0, 0);
}

// ---------------- fused 4x weight transpose + fp32->bf16 ----------------
__global__ __launch_bounds__(256) void transpose_all(const float* __restrict__ Wq,
                                                     const float* __restrict__ Wk,
                                                     const float* __restrict__ Wv,
                                                     const float* __restrict__ Wo,
                                                     u16* __restrict__ Wt) {
  __shared__ u16 t[32][33];
  const float* W = blockIdx.z == 0 ? Wq : blockIdx.z == 1 ? Wk : blockIdx.z == 2 ? Wv : Wo;
  u16* o = Wt + (size_t)blockIdx.z * DMOD * DMOD;
  int bx = blockIdx.x * 32, by = blockIdx.y * 32;
  int x = threadIdx.x, y = threadIdx.y;
  #pragma unroll
  for (int i = 0; i < 32; i += 8)
    t[y + i][x] = f2bf(W[(size_t)(by + y + i) * DMOD + bx + x]);
  __syncthreads();
  #pragma unroll
  for (int i = 0; i < 32; i += 8)
    o[(size_t)(bx + y + i) * DMOD + by + x] = t[x][y + i];
}

// ---------------- x fp32 -> bf16 ----------------
__global__ __launch_bounds__(256) void convert_x(const float* __restrict__ x,
                                                 u16* __restrict__ xb) {
  size_t i = ((size_t)blockIdx.x * 256 + threadIdx.x) * 8;
  float4 f0 = *(const float4*)(x + i);
  float4 f1 = *(const float4*)(x + i + 4);
  uint4 o;
  o.x = pack2bf(f0.x, f0.y); o.y = pack2bf(f0.z, f0.w);
  o.z = pack2bf(f1.x, f1.y); o.w = pack2bf(f1.z, f1.w);
  *(uint4*)(xb + i) = o;
}

// -------- QKV GEMM: [4096x1024]*[3072x1024]^T, m97-style global_load_lds staging --------
__global__ __launch_bounds__(256, 3) void gemm_qkv(const u16* __restrict__ A,
                                                   const u16* __restrict__ Bt,
                                                   u16* __restrict__ Qo,
                                                   u16* __restrict__ Ko,
                                                   u16* __restrict__ Vo) {
  __shared__ __align__(16) u16 As[128 * 32];
  __shared__ __align__(16) u16 Bs[128 * 32];
  const int tid  = threadIdx.x;
  const int lane = tid & 63, wv = tid >> 6;
  const int wm   = wv >> 1, wn = wv & 1;
  const int lrow = lane & 15, quad = lane >> 4;
  const int tileM = blockIdx.x * 128, tileN = blockIdx.y * 128;

  const f32x4 fz = {0.f, 0.f, 0.f, 0.f};
  f32x4 acc[4][4];
  #pragma unroll
  for (int i = 0; i < 4; ++i)
    #pragma unroll
    for (int j = 0; j < 4; ++j) acc[i][j] = fz;

  for (int kt = 0; kt < DMOD; kt += 32) {
    if (kt) __syncthreads();           // previous compute done reading LDS
    #pragma unroll
    for (int i = 0; i < 2; ++i) {
      int idx = i * 256 + tid;         // 512 chunks of 16B = 128 rows x 64B
      gload16(&A [(size_t)(tileM + (idx >> 2)) * DMOD + kt + (idx & 3) * 8], &As[idx * 8]);
      gload16(&Bt[(size_t)(tileN + (idx >> 2)) * DMOD + kt + (idx & 3) * 8], &Bs[idx * 8]);
    }
    __syncthreads();                   // barrier drains vmcnt -> tile visible

    bf16x8 af[4], bfr[4];
    #pragma unroll
    for (int mt = 0; mt < 4; ++mt)
      af[mt] = *(const bf16x8*)(&As[(wm * 64 + mt * 16 + lrow) * 32 + quad * 8]);
    #pragma unroll
    for (int nt = 0; nt < 4; ++nt)
      bfr[nt] = *(const bf16x8*)(&Bs[(wn * 64 + nt * 16 + lrow) * 32 + quad * 8]);
    #pragma unroll
    for (int mt = 0; mt < 4; ++mt)
      #pragma unroll
      for (int nt = 0; nt < 4; ++nt)
        acc[mt][nt] = __builtin_amdgcn_mfma_f32_16x16x32_bf16(af[mt], bfr[nt],
                                                              acc[mt][nt], 0, 0, 0);
  }

  #pragma unroll
  for (int mt = 0; mt < 4; ++mt) {
    #pragma unroll
    for (int nt = 0; nt < 4; ++nt) {
      int gm0 = tileM + wm * 64 + mt * 16 + quad * 4;
      int gn  = tileN + wn * 64 + nt * 16 + lrow;
      int which = gn >> 10, col = gn & 1023;
      int bb = gm0 >> 11, srw0 = gm0 & (SEQ - 1);
      int hh = col >> 6, dki = col & (DKH - 1);
      size_t bhi = (size_t)(bb * NH + hh);
      if (which == 0) {
        #pragma unroll
        for (int r = 0; r < 4; ++r)
          Qo[(bhi * SEQ + srw0 + r) * DKH + dki] = f2bf(acc[mt][nt][r] * QSCALE);
      } else if (which == 1) {
        #pragma unroll
        for (int r = 0; r < 4; ++r)
          Ko[(bhi * SEQ + srw0 + r) * DKH + dki] = f2bf(acc[mt][nt][r]);
      } else {
        uint2 pk;
        pk.x = pack2bf(acc[mt][nt][0], acc[mt][nt][1]);
        pk.y = pack2bf(acc[mt][nt][2], acc[mt][nt][3]);
        *(uint2*)(&Vo[(((bhi * (SEQ / 4)) + (srw0 >> 2)) * DKH + dki) * 4]) = pk;
      }
    }
  }
}

// -------- out GEMM: [4096x1024]*[1024x1024]^T -> fp32, 128x64, global_load_lds --------
__global__ __launch_bounds__(256, 3) void gemm_out(const u16* __restrict__ A,
                                                   const u16* __restrict__ Bt,
                                                   float* __restrict__ Co) {
  __shared__ __align__(16) u16 As[128 * 32];
  __shared__ __align__(16) u16 Bs[64 * 32];
  const int tid  = threadIdx.x;
  const int lane = tid & 63, wv = tid >> 6;
  const int wm   = wv & 1, wn = wv >> 1;
  const int lrow = lane & 15, quad = lane >> 4;
  const int tileM = blockIdx.x * 128, tileN = blockIdx.y * 64;

  const f32x4 fz = {0.f, 0.f, 0.f, 0.f};
  f32x4 acc[4][2];
  #pragma unroll
  for (int i = 0; i < 4; ++i) { acc[i][0] = fz; acc[i][1] = fz; }

  for (int kt = 0; kt < DMOD; kt += 32) {
    if (kt) __syncthreads();
    #pragma unroll
    for (int i = 0; i < 2; ++i) {
      int idx = i * 256 + tid;
      gload16(&A[(size_t)(tileM + (idx >> 2)) * DMOD + kt + (idx & 3) * 8], &As[idx * 8]);
    }
    gload16(&Bt[(size_t)(tileN + (tid >> 2)) * DMOD + kt + (tid & 3) * 8], &Bs[tid * 8]);
    __syncthreads();

    bf16x8 af[4], bfr[2];
    #pragma unroll
    for (int mt = 0; mt < 4; ++mt)
      af[mt] = *(const bf16x8*)(&As[(wm * 64 + mt * 16 + lrow) * 32 + quad * 8]);
    #pragma unroll
    for (int nt = 0; nt < 2; ++nt)
      bfr[nt] = *(const bf16x8*)(&Bs[(wn * 32 + nt * 16 + lrow) * 32 + quad * 8]);
    #pragma unroll
    for (int mt = 0; mt < 4; ++mt)
      #pragma unroll
      for (int nt = 0; nt < 2; ++nt)
        acc[mt][nt] = __builtin_amdgcn_mfma_f32_16x16x32_bf16(af[mt], bfr[nt],
                                                              acc[mt][nt], 0, 0, 0);
  }

  #pragma unroll
  for (int mt = 0; mt < 4; ++mt)
    #pragma unroll
    for (int nt = 0; nt < 2; ++nt)
      #pragma unroll
      for (int r = 0; r < 4; ++r) {
        int gm = tileM + wm * 64 + mt * 16 + quad * 4 + r;
        int gn = tileN + wn * 32 + nt * 16 + lrow;
        Co[(size_t)gm * DMOD + gn] = acc[mt][nt][r];
      }
}

// ---------------- causal flash attention: S^T, uniform blocks + gload dbuf pipeline ----------------
// Round-6: 128-thread blocks (2 waves x 32 q-rows = 64-row q-tile). Each block handles
// q-tiles {y, 31-y} SEQUENTIALLY -> exactly 17 k-tile iters per block (uniform: no tail,
// no dispatch-order dependence). Grid (32,16) = 512 blocks = 2/CU constant.
// K/V DOUBLE-buffered via global_load_lds (zero staging regs): per iter
// {issue 16 gloads -> buf^1; compute buf; __syncthreads}. The compiler's vmcnt(0)
// before s_barrier drains loads issued ~1000cyc earlier (L2 ~300cyc) -> stage stall ~0.
// One barrier/iter. LDS 64KB + 8.5KB O-staging = 72.5KB -> 2 blocks/CU.
// Same 16B-chunk XOR swizzles as round 5 (verified: conflicts 1.84M -> 393K).
#define OP 68

__global__ __launch_bounds__(128, 2) void attn_k(const u16* __restrict__ Q,
                                                 const u16* __restrict__ Kg,
                                                 const u16* __restrict__ Vg,
                                                 u16* __restrict__ Og) {
  __shared__ __align__(16) u16 KsA[128 * 64];
  __shared__ __align__(16) u16 VsA[32 * 256];
  __shared__ __align__(16) u16 KsB[128 * 64];
  __shared__ __align__(16) u16 VsB[32 * 256];
  __shared__ __align__(16) u16 Os[64 * OP];

  const int tid  = threadIdx.x;
  const int lane = tid & 63, w = tid >> 6;          // w in 0..1
  const int lrow = lane & 15, quad = lane >> 4;
  const int bh = blockIdx.x;
  const int y  = blockIdx.y;                        // 0..15
  const int b = bh >> 4, h = bh & 15;
  const int qA = y, qB = 31 - y;                    // 64-row q-tiles, tiles(qA)+tiles(qB)=17
  const int tA = y >> 1;                            // qA's diagonal iter index

  const u16* Qbh = Q  + (size_t)bh * SEQ * DKH;
  const u16* Kbh = Kg + (size_t)bh * SEQ * DKH;
  const u16* Vbh = Vg + (size_t)bh * SEQ * DKH;     // [s/4][dk][4]

  // Q fragments for current half (strips 2w, 2w+1)
  bf16x8 bq[2][2];
  #pragma unroll
  for (int s = 0; s < 2; ++s)
    #pragma unroll
    for (int kk = 0; kk < 2; ++kk)
      bq[s][kk] = *(const bf16x8*)(&Qbh[(size_t)(qA * 64 + (2 * w + s) * 16 + lrow) * DKH
                                        + kk * 32 + quad * 8]);

  // stage k-tile jn into (Kd, Vd); dest linear in tid, source inverse-swizzled
#define STAGE(Kd, Vd, jn)                                                              \
  {                                                                                    \
    _Pragma("unroll")                                                                  \
    for (int i_ = 0; i_ < 8; ++i_) {                                                   \
      int cD = i_ * 128 + tid;                                                         \
      int r_ = cD >> 3, c_ = cD & 7;                                                   \
      gload16(&Kbh[(size_t)((jn) * 128 + r_) * DKH + ((c_ ^ (r_ & 7)) << 3)],          \
              &(Kd)[cD * 8]);                                                          \
    }                                                                                  \
    _Pragma("unroll")                                                                  \
    for (int i_ = 0; i_ < 8; ++i_) {                                                   \
      int cD = i_ * 128 + tid;                                                         \
      int sq_ = cD >> 5, c_ = cD & 31;                                                 \
      gload16(&Vbh[(size_t)((jn) * 32 + sq_) * 256 + ((c_ ^ (sq_ & 7)) << 3)],         \
              &(Vd)[cD * 8]);                                                          \
    }                                                                                  \
  }

  STAGE(KsA, VsA, 0);                  // prologue: first tile of qA
  __syncthreads();                     // vmcnt(0) drain -> buf A ready

  const f32x4 fz = {0.f, 0.f, 0.f, 0.f};
  f32x4 oacc[2][4];
  #pragma unroll
  for (int s = 0; s < 2; ++s)
    #pragma unroll
    for (int d = 0; d < 4; ++d) oacc[s][d] = fz;
  float lsum[2] = {0.f, 0.f};

  int cur = 0;
  for (int t = 0; t < 17; ++t) {
    const int half = (t > tA) ? 1 : 0;
    const int qcur = half ? qB : qA;
    u16* Ks = cur ? KsB : KsA;
    u16* Vs = cur ? VsB : VsA;
    u16* Kn = cur ? KsA : KsB;
    u16* Vn = cur ? VsA : VsB;

    if (t < 16) {                      // issue next tile into the other buffer
      const int tn = t + 1;
      const int jn = (tn > tA) ? (tn - tA - 1) : tn;
      STAGE(Kn, Vn, jn);
    }

    const bool diag = (t == tA) || (t == 16);
    if (!diag) {
      __builtin_amdgcn_s_setprio(1);
      // full k-tile for both strips; every ak/av LDS read feeds 2 MFMAs
      f32x4 sacc[2][8];
      #pragma unroll
      for (int s = 0; s < 2; ++s)
        #pragma unroll
        for (int m = 0; m < 8; ++m) sacc[s][m] = fz;
      #pragma unroll
      for (int kk = 0; kk < 2; ++kk)
        #pragma unroll
        for (int m = 0; m < 8; ++m) {
          bf16x8 ak = *(const bf16x8*)(&Ks[(m * 16 + lrow) * 64
                                           + (((kk * 4 + quad) ^ (lrow & 7)) << 3)]);
          sacc[0][m] = __builtin_amdgcn_mfma_f32_16x16x32_bf16(ak, bq[0][kk], sacc[0][m], 0, 0, 0);
          sacc[1][m] = __builtin_amdgcn_mfma_f32_16x16x32_bf16(ak, bq[1][kk], sacc[1][m], 0, 0, 0);
        }
      #pragma unroll
      for (int m = 0; m < 8; ++m) {
        float p00 = EXP2(sacc[0][m][0]), p01 = EXP2(sacc[0][m][1]);
        float p02 = EXP2(sacc[0][m][2]), p03 = EXP2(sacc[0][m][3]);
        float p10 = EXP2(sacc[1][m][0]), p11 = EXP2(sacc[1][m][1]);
        float p12 = EXP2(sacc[1][m][2]), p13 = EXP2(sacc[1][m][3]);
        lsum[0] += (p00 + p01) + (p02 + p03);
        lsum[1] += (p10 + p11) + (p12 + p13);
        s16x4 pk0 = pk4bf(p00, p01, p02, p03);
        s16x4 pk1 = pk4bf(p10, p11, p12, p13);
        const int sq = m * 4 + quad;
        #pragma unroll
        for (int d = 0; d < 4; ++d) {
          int dk = d * 16 + lrow;
          s16x4 av = *(const s16x4*)(&Vs[sq * 256
                                         + ((((dk >> 1) ^ (sq & 7)) << 3) | ((dk & 1) << 2))]);
          oacc[0][d] = mfma16(av, pk0, oacc[0][d]);
          oacc[1][d] = mfma16(av, pk1, oacc[1][d]);
        }
      }
      __builtin_amdgcn_s_setprio(0);
    } else {
      // diagonal k-tile: strip local index L = qoff*4 + 2w+s within the 128-row tile
      const int qoff = qcur & 1;
      #pragma unroll
      for (int s = 0; s < 2; ++s) {
        const int L = qoff * 4 + 2 * w + s;
        for (int m = 0; m < L; ++m) {
          f32x4 sv = fz;
          #pragma unroll
          for (int kk = 0; kk < 2; ++kk) {
            bf16x8 ak = *(const bf16x8*)(&Ks[(m * 16 + lrow) * 64
                                             + (((kk * 4 + quad) ^ (lrow & 7)) << 3)]);
            sv = __builtin_amdgcn_mfma_f32_16x16x32_bf16(ak, bq[s][kk], sv, 0, 0, 0);
          }
          float p0 = EXP2(sv[0]), p1 = EXP2(sv[1]), p2 = EXP2(sv[2]), p3 = EXP2(sv[3]);
          lsum[s] += (p0 + p1) + (p2 + p3);
          s16x4 pk = pk4bf(p0, p1, p2, p3);
          const int sq = m * 4 + quad;
          #pragma unroll
          for (int d = 0; d < 4; ++d) {
            int dk = d * 16 + lrow;
            s16x4 av = *(const s16x4*)(&Vs[sq * 256
                                           + ((((dk >> 1) ^ (sq & 7)) << 3) | ((dk & 1) << 2))]);
            oacc[s][d] = mfma16(av, pk, oacc[s][d]);
          }
        }
        { // m == L : masked diagonal strip (k > q -> 0)
          f32x4 sv = fz;
          #pragma unroll
          for (int kk = 0; kk < 2; ++kk) {
            bf16x8 ak = *(const bf16x8*)(&Ks[(L * 16 + lrow) * 64
                                             + (((kk * 4 + quad) ^ (lrow & 7)) << 3)]);
            sv = __builtin_amdgcn_mfma_f32_16x16x32_bf16(ak, bq[s][kk], sv, 0, 0, 0);
          }
          float p[4];
          #pragma unroll
          for (int r = 0; r < 4; ++r)
            p[r] = (quad * 4 + r > lrow) ? 0.f : EXP2(sv[r]);
          lsum[s] += (p[0] + p[1]) + (p[2] + p[3]);
          s16x4 pk = pk4bf(p[0], p[1], p[2], p[3]);
          const int sq = L * 4 + quad;
          #pragma unroll
          for (int d = 0; d < 4; ++d) {
            int dk = d * 16 + lrow;
            s16x4 av = *(const s16x4*)(&Vs[sq * 256
                                           + ((((dk >> 1) ^ (sq & 7)) << 3) | ((dk & 1) << 2))]);
            oacc[s][d] = mfma16(av, pk, oacc[s][d]);
          }
        }
      }

      // ---- epilogue for this half: normalize, stage to Os, coalesced write ----
      float inv[2];
      #pragma unroll
      for (int s = 0; s < 2; ++s) {
        float v = lsum[s];
        v += __shfl_xor(v, 16, 64);
        v += __shfl_xor(v, 32, 64);
        inv[s] = 1.f / v;
      }
      #pragma unroll
      for (int s = 0; s < 2; ++s) {
        int row = (2 * w + s) * 16 + lrow;
        #pragma unroll
        for (int d = 0; d < 4; ++d) {
          uint2 pkk;
          pkk.x = pack2bf(oacc[s][d][0] * inv[s], oacc[s][d][1] * inv[s]);
          pkk.y = pack2bf(oacc[s][d][2] * inv[s], oacc[s][d][3] * inv[s]);
          *(uint2*)(&Os[row * OP + d * 16 + quad * 4]) = pkk;
        }
      }
      __syncthreads();                 // Os fully written
      #pragma unroll
      for (int k = 0; k < 4; ++k) {
        int c = k * 128 + tid;         // 512 chunks of 16B = 64 rows x 128B
        int row = c >> 3, ch = c & 7;
        uint4 v = *(const uint4*)(&Os[row * OP + ch * 8]);
        *(uint4*)(&Og[(size_t)(b * SEQ + qcur * 64 + row) * DMOD + h * DKH + ch * 8]) = v;
      }

      if (!half) {                     // switch to qB: reset accum, reload Q frags
        #pragma unroll
        for (int s = 0; s < 2; ++s)
          #pragma unroll
          for (int d = 0; d < 4; ++d) oacc[s][d] = fz;
        lsum[0] = 0.f; lsum[1] = 0.f;
        #pragma unroll
        for (int s = 0; s < 2; ++s)
          #pragma unroll
          for (int kk = 0; kk < 2; ++kk)
            bq[s][kk] = *(const bf16x8*)(&Qbh[(size_t)(qB * 64 + (2 * w + s) * 16 + lrow) * DKH
                                              + kk * 32 + quad * 8]);
      }
    }

    __syncthreads();                   // drains staged loads; everyone done with buf[cur]
    cur ^= 1;
  }
#undef STAGE
}

// ---------------- launch ----------------
extern "C" void kernel_launch(void* const* d_in, const int* in_sizes, int n_in,
                              void* d_out, int out_size, void* d_ws, size_t ws_size,
                              hipStream_t stream) {
  const float* x  = (const float*)d_in[0];
  const float* Wq = (const float*)d_in[1];
  const float* Wk = (const float*)d_in[2];
  const float* Wv = (const float*)d_in[3];
  const float* Wo = (const float*)d_in[4];

  u16* ws = (u16*)d_ws;
  const size_t WSZ = (size_t)DMOD * DMOD;
  const size_t TSZ = (size_t)BAT * NH * SEQ * DKH;
  u16* Wt  = ws;                 // 4 transposed weights
  u16* Wto = Wt + 3 * WSZ;
  u16* xb  = Wt + 4 * WSZ;       // x bf16; dead after QKV -> reused as Ob
  u16* Qb  = xb + TSZ;
  u16* Kb  = Qb + TSZ;
  u16* Vb  = Kb + TSZ;           // [b,h,s/4,dk,4]
  u16* Ob  = xb;

  transpose_all<<<dim3(32, 32, 4), dim3(32, 8), 0, stream>>>(Wq, Wk, Wv, Wo, Wt);
  convert_x<<<dim3(2048), 256, 0, stream>>>(x, xb);

  gemm_qkv<<<dim3(32, 24), 256, 0, stream>>>(xb, Wt, Qb, Kb, Vb);

  attn_k<<<dim3(32, 16), 128, 0, stream>>>(Qb, Kb, Vb, Ob);

  gemm_out<<<dim3(32, 16), 256, 0, stream>>>(Ob, Wto, (float*)d_out);
}

// Round 7
// 170.420 us; speedup vs baseline: 1.6887x; 1.0220x over previous
//
#include <hip/hip_runtime.h>

typedef unsigned short u16;
typedef unsigned int   u32;

using bf16x8 = __attribute__((ext_vector_type(8))) __bf16;
using bf16x4 = __attribute__((ext_vector_type(4))) __bf16;
using f32x4  = __attribute__((ext_vector_type(4))) float;
using s16x4  = __attribute__((ext_vector_type(4))) short;

#define NH    16
#define DKH   64
#define SEQ   2048
#define BAT   2
#define DMOD  1024

// 0.125 (1/sqrt(dk)) * log2(e): scores in log2 domain -> p = exp2(s)
#define QSCALE 0.18033688011112042f

__device__ __forceinline__ u16 f2bf(float f) {
  union { float f; u32 u; } v; v.f = f;
  u32 r = v.u + 0x7fffu + ((v.u >> 16) & 1u);
  return (u16)(r >> 16);
}

__device__ __forceinline__ u32 pack2bf(float a, float b) {
  union { float f; u32 u; } x, y; x.f = a; y.f = b;
  u32 ua = x.u + 0x7fffu + ((x.u >> 16) & 1u);
  u32 ub = y.u + 0x7fffu + ((y.u >> 16) & 1u);
  return __builtin_amdgcn_perm(ub, ua, 0x07060302u);
}

// compiler emits v_cvt_pk_bf16_f32 pairs
__device__ __forceinline__ s16x4 pk4bf(float a, float b, float c, float d) {
  union { bf16x4 bv; s16x4 sv; } u;
  u.bv[0] = (__bf16)a; u.bv[1] = (__bf16)b; u.bv[2] = (__bf16)c; u.bv[3] = (__bf16)d;
  return u.sv;
}

#if __has_builtin(__builtin_amdgcn_exp2f)
#define EXP2(x) __builtin_amdgcn_exp2f(x)
#else
#define EXP2(x) exp2f(x)
#endif

#if __has_builtin(__builtin_amdgcn_mfma_f32_16x16x16bf16_1k)
__device__ __forceinline__ f32x4 mfma16(s16x4 a, s16x4 b, f32x4 c) {
  return __builtin_amdgcn_mfma_f32_16x16x16bf16_1k(a, b, c, 0, 0, 0);
}
#else
__device__ __forceinline__ f32x4 mfma16(s16x4 a, s16x4 b, f32x4 c) {
  f32x4 d;
  asm volatile("v_mfma_f32_16x16x16_bf16 %0, %1, %2, %3\n\ts_nop 7\n\ts_nop 7"
               : "=v"(d) : "v"(a), "v"(b), "v"(c));
  return d;
}
#endif

// async global->LDS, 16B per lane. Dest must be linear in tid within each wave.
typedef const __attribute__((address_space(1))) u32 glb_u32;
typedef __attribute__((address_space(3))) u32 lds_u32;
__device__ __forceinline__ void gload16(const u16* g, u16* l) {
  __builtin_amdgcn_global_load_lds((glb_u32*)(const void*)g, (lds_u32*)(void*)l, 16, 0, 0);
}

// ---------------- fused 4x weight transpose + fp32->bf16 ----------------
__global__ __launch_bounds__(256) void transpose_all(const float* __restrict__ Wq,
                                                     const float* __restrict__ Wk,
                                                     const float* __restrict__ Wv,
                                                     const float* __restrict__ Wo,
                                                     u16* __restrict__ Wt) {
  __shared__ u16 t[32][33];
  const float* W = blockIdx.z == 0 ? Wq : blockIdx.z == 1 ? Wk : blockIdx.z == 2 ? Wv : Wo;
  u16* o = Wt + (size_t)blockIdx.z * DMOD * DMOD;
  int bx = blockIdx.x * 32, by = blockIdx.y * 32;
  int x = threadIdx.x, y = threadIdx.y;
  #pragma unroll
  for (int i = 0; i < 32; i += 8)
    t[y + i][x] = f2bf(W[(size_t)(by + y + i) * DMOD + bx + x]);
  __syncthreads();
  #pragma unroll
  for (int i = 0; i < 32; i += 8)
    o[(size_t)(bx + y + i) * DMOD + by + x] = t[x][y + i];
}

// ---------------- x fp32 -> bf16 ----------------
__global__ __launch_bounds__(256) void convert_x(const float* __restrict__ x,
                                                 u16* __restrict__ xb) {
  size_t i = ((size_t)blockIdx.x * 256 + threadIdx.x) * 8;
  float4 f0 = *(const float4*)(x + i);
  float4 f1 = *(const float4*)(x + i + 4);
  uint4 o;
  o.x = pack2bf(f0.x, f0.y); o.y = pack2bf(f0.z, f0.w);
  o.z = pack2bf(f1.x, f1.y); o.w = pack2bf(f1.z, f1.w);
  *(uint4*)(xb + i) = o;
}

// -------- QKV GEMM: [4096x1024]*[3072x1024]^T, m97-style global_load_lds staging --------
__global__ __launch_bounds__(256, 3) void gemm_qkv(const u16* __restrict__ A,
                                                   const u16* __restrict__ Bt,
                                                   u16* __restrict__ Qo,
                                                   u16* __restrict__ Ko,
                                                   u16* __restrict__ Vo) {
  __shared__ __align__(16) u16 As[128 * 32];
  __shared__ __align__(16) u16 Bs[128 * 32];
  const int tid  = threadIdx.x;
  const int lane = tid & 63, wv = tid >> 6;
  const int wm   = wv >> 1, wn = wv & 1;
  const int lrow = lane & 15, quad = lane >> 4;
  const int tileM = blockIdx.x * 128, tileN = blockIdx.y * 128;

  const f32x4 fz = {0.f, 0.f, 0.f, 0.f};
  f32x4 acc[4][4];
  #pragma unroll
  for (int i = 0; i < 4; ++i)
    #pragma unroll
    for (int j = 0; j < 4; ++j) acc[i][j] = fz;

  for (int kt = 0; kt < DMOD; kt += 32) {
    if (kt) __syncthreads();
    #pragma unroll
    for (int i = 0; i < 2; ++i) {
      int idx = i * 256 + tid;
      gload16(&A [(size_t)(tileM + (idx >> 2)) * DMOD + kt + (idx & 3) * 8], &As[idx * 8]);
      gload16(&Bt[(size_t)(tileN + (idx >> 2)) * DMOD + kt + (idx & 3) * 8], &Bs[idx * 8]);
    }
    __syncthreads();

    bf16x8 af[4], bfr[4];
    #pragma unroll
    for (int mt = 0; mt < 4; ++mt)
      af[mt] = *(const bf16x8*)(&As[(wm * 64 + mt * 16 + lrow) * 32 + quad * 8]);
    #pragma unroll
    for (int nt = 0; nt < 4; ++nt)
      bfr[nt] = *(const bf16x8*)(&Bs[(wn * 64 + nt * 16 + lrow) * 32 + quad * 8]);
    #pragma unroll
    for (int mt = 0; mt < 4; ++mt)
      #pragma unroll
      for (int nt = 0; nt < 4; ++nt)
        acc[mt][nt] = __builtin_amdgcn_mfma_f32_16x16x32_bf16(af[mt], bfr[nt],
                                                              acc[mt][nt], 0, 0, 0);
  }

  #pragma unroll
  for (int mt = 0; mt < 4; ++mt) {
    #pragma unroll
    for (int nt = 0; nt < 4; ++nt) {
      int gm0 = tileM + wm * 64 + mt * 16 + quad * 4;
      int gn  = tileN + wn * 64 + nt * 16 + lrow;
      int which = gn >> 10, col = gn & 1023;
      int bb = gm0 >> 11, srw0 = gm0 & (SEQ - 1);
      int hh = col >> 6, dki = col & (DKH - 1);
      size_t bhi = (size_t)(bb * NH + hh);
      if (which == 0) {
        #pragma unroll
        for (int r = 0; r < 4; ++r)
          Qo[(bhi * SEQ + srw0 + r) * DKH + dki] = f2bf(acc[mt][nt][r] * QSCALE);
      } else if (which == 1) {
        #pragma unroll
        for (int r = 0; r < 4; ++r)
          Ko[(bhi * SEQ + srw0 + r) * DKH + dki] = f2bf(acc[mt][nt][r]);
      } else {
        uint2 pk;
        pk.x = pack2bf(acc[mt][nt][0], acc[mt][nt][1]);
        pk.y = pack2bf(acc[mt][nt][2], acc[mt][nt][3]);
        *(uint2*)(&Vo[(((bhi * (SEQ / 4)) + (srw0 >> 2)) * DKH + dki) * 4]) = pk;
      }
    }
  }
}

// -------- out GEMM: [4096x1024]*[1024x1024]^T -> fp32, 128x64, global_load_lds --------
__global__ __launch_bounds__(256, 3) void gemm_out(const u16* __restrict__ A,
                                                   const u16* __restrict__ Bt,
                                                   float* __restrict__ Co) {
  __shared__ __align__(16) u16 As[128 * 32];
  __shared__ __align__(16) u16 Bs[64 * 32];
  const int tid  = threadIdx.x;
  const int lane = tid & 63, wv = tid >> 6;
  const int wm   = wv & 1, wn = wv >> 1;
  const int lrow = lane & 15, quad = lane >> 4;
  const int tileM = blockIdx.x * 128, tileN = blockIdx.y * 64;

  const f32x4 fz = {0.f, 0.f, 0.f, 0.f};
  f32x4 acc[4][2];
  #pragma unroll
  for (int i = 0; i < 4; ++i) { acc[i][0] = fz; acc[i][1] = fz; }

  for (int kt = 0; kt < DMOD; kt += 32) {
    if (kt) __syncthreads();
    #pragma unroll
    for (int i = 0; i < 2; ++i) {
      int idx = i * 256 + tid;
      gload16(&A[(size_t)(tileM + (idx >> 2)) * DMOD + kt + (idx & 3) * 8], &As[idx * 8]);
    }
    gload16(&Bt[(size_t)(tileN + (tid >> 2)) * DMOD + kt + (tid & 3) * 8], &Bs[tid * 8]);
    __syncthreads();

    bf16x8 af[4], bfr[2];
    #pragma unroll
    for (int mt = 0; mt < 4; ++mt)
      af[mt] = *(const bf16x8*)(&As[(wm * 64 + mt * 16 + lrow) * 32 + quad * 8]);
    #pragma unroll
    for (int nt = 0; nt < 2; ++nt)
      bfr[nt] = *(const bf16x8*)(&Bs[(wn * 32 + nt * 16 + lrow) * 32 + quad * 8]);
    #pragma unroll
    for (int mt = 0; mt < 4; ++mt)
      #pragma unroll
      for (int nt = 0; nt < 2; ++nt)
        acc[mt][nt] = __builtin_amdgcn_mfma_f32_16x16x32_bf16(af[mt], bfr[nt],
                                                              acc[mt][nt], 0, 0, 0);
  }

  #pragma unroll
  for (int mt = 0; mt < 4; ++mt)
    #pragma unroll
    for (int nt = 0; nt < 2; ++nt)
      #pragma unroll
      for (int r = 0; r < 4; ++r) {
        int gm = tileM + wm * 64 + mt * 16 + quad * 4 + r;
        int gn = tileN + wn * 32 + nt * 16 + lrow;
        Co[(size_t)gm * DMOD + gn] = acc[mt][nt][r];
      }
}

// ------------- causal flash attention: split-k wave-groups, in-LDS combine -------------
// Round-7: 256-thread blocks = 2 wave-groups of 2 waves. BOTH groups own the same
// 64 q-rows (2 strips/wave -> ak/av read sharing kept). Job list: [qA=y: k-tiles 0..y]
// then [qB=31-y: k-tiles 0..31-y] (64-row k-tiles). Group g takes the g-parity jobs of
// each q-tile -> ALWAYS 17 lockstep steps (uniform; 1 barrier/step; <=1 idle
// group-step per q-tile). All 256 threads stage both groups' next tiles per step via
// global_load_lds double-buffer (4 x 16KB = 64KB). Split-k partials combine IN LDS
// (O=(O0+O1)/(l0+l1), no max-track -> plain sums; 8.7KB scratch, no global roundtrip).
// LDS 72.6KB -> 2 blocks/CU = 8 waves/CU = 2 waves/SIMD (round-6 was 1/SIMD,
// latency-bound at 6100 cyc/iter vs ~850 issue). Grid (32,16)=512 uniform blocks.
#define OPAD 68

__global__ __launch_bounds__(256, 2) void attn_k(const u16* __restrict__ Q,
                                                 const u16* __restrict__ Kg,
                                                 const u16* __restrict__ Vg,
                                                 u16* __restrict__ Og) {
  __shared__ __align__(16) u16 Ksb[2][2][64 * 64];    // [group][dbuf], swizzled
  __shared__ __align__(16) u16 Vsb[2][2][16 * 256];
  __shared__ __align__(16) u16 Osc[64 * OPAD];        // f32[32][OPAD] / u16[64][OPAD]
  __shared__ float Lsc[32];

  const int tid  = threadIdx.x;
  const int lane = tid & 63, w = tid >> 6;            // w in 0..3
  const int g    = w >> 1,  wg = w & 1;               // group, wave-in-group
  const int lrow = lane & 15, quad = lane >> 4;
  const int bh = blockIdx.x, y = blockIdx.y;          // y in 0..15
  const int b = bh >> 4, h = bh & 15;
  const int qB = 31 - y;
  const int sAend = y >> 1;                           // qA's last step index

  const u16* Qbh = Q  + (size_t)bh * SEQ * DKH;
  const u16* Kbh = Kg + (size_t)bh * SEQ * DKH;
  const u16* Vbh = Vg + (size_t)bh * SEQ * DKH;       // [s/4][dk][4]

  const f32x4 fz = {0.f, 0.f, 0.f, 0.f};
  f32x4 oacc[2][4];
  float lsum[2];
  bf16x8 bq[2][2];

  // decode step s, group gg -> (q-tile, k-tile j, valid)
#define DEC(s_, g_, qt_, j_, v_)                                                   \
  { if ((s_) <= sAend) { qt_ = y;  j_ = 2 * (s_) + (g_);              v_ = (j_ <= y);  } \
    else               { qt_ = qB; j_ = 2 * ((s_) - sAend - 1) + (g_); v_ = (j_ <= qB); } }

  // stage 64-row k-tile j into group gg's buffer p (dest linear, src inverse-swizzled)
#define STAGE1(gg, p_, j_)                                                          \
  { _Pragma("unroll")                                                               \
    for (int i_ = 0; i_ < 2; ++i_) {                                                \
      int cD = i_ * 256 + tid; int r_ = cD >> 3, c_ = cD & 7;                       \
      gload16(&Kbh[(size_t)((j_) * 64 + r_) * DKH + ((c_ ^ (r_ & 7)) << 3)],        \
              &Ksb[gg][p_][cD * 8]); }                                              \
    _Pragma("unroll")                                                               \
    for (int i_ = 0; i_ < 2; ++i_) {                                                \
      int cD = i_ * 256 + tid; int sq_ = cD >> 5, c_ = cD & 31;                     \
      gload16(&Vbh[(size_t)((j_) * 16 + sq_) * 256 + ((c_ ^ (sq_ & 7)) << 3)],      \
              &Vsb[gg][p_][cD * 8]); } }

#define LOADQ(qt_)                                                                  \
  { _Pragma("unroll")                                                               \
    for (int s_ = 0; s_ < 2; ++s_)                                                  \
      _Pragma("unroll")                                                             \
      for (int kk_ = 0; kk_ < 2; ++kk_)                                             \
        bq[s_][kk_] = *(const bf16x8*)(&Qbh[(size_t)((qt_) * 64 + wg * 32 + s_ * 16 \
                                            + lrow) * DKH + kk_ * 32 + quad * 8]); }

  // per-q-tile epilogue: group1 -> LDS partials (2 phases), group0 combines+writes
  auto EPI = [&](int qt) {
    float ls[2];
    #pragma unroll
    for (int s2 = 0; s2 < 2; ++s2) {
      float v = lsum[s2];
      v += __shfl_xor(v, 16, 64);
      v += __shfl_xor(v, 32, 64);
      ls[s2] = v;
    }
    float* OscF = (float*)Osc;
    #pragma unroll
    for (int ph = 0; ph < 2; ++ph) {
      if (g == 1) {
        int srow = wg * 16 + lrow;
        #pragma unroll
        for (int d = 0; d < 4; ++d)
          *(f32x4*)(&OscF[srow * OPAD + d * 16 + quad * 4]) = oacc[ph][d];
        if (quad == 0) Lsc[srow] = ls[ph];
      }
      __syncthreads();
      if (g == 0) {
        int srow = wg * 16 + lrow;
        ls[ph] += Lsc[srow];
        #pragma unroll
        for (int d = 0; d < 4; ++d) {
          f32x4 ov = *(const f32x4*)(&OscF[srow * OPAD + d * 16 + quad * 4]);
          oacc[ph][d] += ov;
        }
      }
      __syncthreads();
    }
    if (g == 0) {
      #pragma unroll
      for (int s2 = 0; s2 < 2; ++s2) {
        float inv = 1.f / ls[s2];
        int row = wg * 32 + s2 * 16 + lrow;
        #pragma unroll
        for (int d = 0; d < 4; ++d) {
          uint2 pkk;
          pkk.x = pack2bf(oacc[s2][d][0] * inv, oacc[s2][d][1] * inv);
          pkk.y = pack2bf(oacc[s2][d][2] * inv, oacc[s2][d][3] * inv);
          *(uint2*)(&Osc[row * OPAD + d * 16 + quad * 4]) = pkk;
        }
      }
    }
    __syncthreads();
    #pragma unroll
    for (int k2 = 0; k2 < 2; ++k2) {
      int c2 = k2 * 256 + tid;                    // 512 chunks = 64 rows x 128B
      int row = c2 >> 3, ch = c2 & 7;
      uint4 vv = *(const uint4*)(&Osc[row * OPAD + ch * 8]);
      *(uint4*)(&Og[(size_t)(b * SEQ + qt * 64 + row) * DMOD + h * DKH + ch * 8]) = vv;
    }
  };

  // ---- prologue: stage step-0 tiles, load qA fragments ----
  { int qt0, j0; bool v0;
    DEC(0, 0, qt0, j0, v0); if (v0) STAGE1(0, 0, j0);
    DEC(0, 1, qt0, j0, v0); if (v0) STAGE1(1, 0, j0);
  }
  LOADQ(y);
  #pragma unroll
  for (int s2 = 0; s2 < 2; ++s2) {
    oacc[s2][0] = fz; oacc[s2][1] = fz; oacc[s2][2] = fz; oacc[s2][3] = fz;
    lsum[s2] = 0.f;
  }
  __syncthreads();                                 // drain -> step-0 tiles ready

  for (int s = 0; s <= 16; ++s) {
    const int p = s & 1;

    if (s < 16) {                                  // issue next-step tiles (both groups)
      int qtn, jn; bool vn;
      DEC(s + 1, 0, qtn, jn, vn); if (vn) STAGE1(0, p ^ 1, jn);
      DEC(s + 1, 1, qtn, jn, vn); if (vn) STAGE1(1, p ^ 1, jn);
    }

    int qt, j; bool valid;
    DEC(s, g, qt, j, valid);
    if (valid) {
      const u16* Ks = Ksb[g][p];
      const u16* Vs = Vsb[g][p];
      if (j < qt) {
        __builtin_amdgcn_s_setprio(1);
        f32x4 sacc[2][4];
        #pragma unroll
        for (int s2 = 0; s2 < 2; ++s2)
          #pragma unroll
          for (int m = 0; m < 4; ++m) sacc[s2][m] = fz;
        #pragma unroll
        for (int kk = 0; kk < 2; ++kk)
          #pragma unroll
          for (int m = 0; m < 4; ++m) {
            bf16x8 ak = *(const bf16x8*)(&Ks[(m * 16 + lrow) * 64
                                             + (((kk * 4 + quad) ^ (lrow & 7)) << 3)]);
            sacc[0][m] = __builtin_amdgcn_mfma_f32_16x16x32_bf16(ak, bq[0][kk], sacc[0][m], 0, 0, 0);
            sacc[1][m] = __builtin_amdgcn_mfma_f32_16x16x32_bf16(ak, bq[1][kk], sacc[1][m], 0, 0, 0);
          }
        #pragma unroll
        for (int m = 0; m < 4; ++m) {
          float p00 = EXP2(sacc[0][m][0]), p01 = EXP2(sacc[0][m][1]);
          float p02 = EXP2(sacc[0][m][2]), p03 = EXP2(sacc[0][m][3]);
          float p10 = EXP2(sacc[1][m][0]), p11 = EXP2(sacc[1][m][1]);
          float p12 = EXP2(sacc[1][m][2]), p13 = EXP2(sacc[1][m][3]);
          lsum[0] += (p00 + p01) + (p02 + p03);
          lsum[1] += (p10 + p11) + (p12 + p13);
          s16x4 pk0 = pk4bf(p00, p01, p02, p03);
          s16x4 pk1 = pk4bf(p10, p11, p12, p13);
          const int sq = m * 4 + quad;
          #pragma unroll
          for (int d = 0; d < 4; ++d) {
            int dk = d * 16 + lrow;
            s16x4 av = *(const s16x4*)(&Vs[sq * 256
                                           + ((((dk >> 1) ^ (sq & 7)) << 3) | ((dk & 1) << 2))]);
            oacc[0][d] = mfma16(av, pk0, oacc[0][d]);
            oacc[1][d] = mfma16(av, pk1, oacc[1][d]);
          }
        }
        __builtin_amdgcn_s_setprio(0);
      } else {
        // diagonal 64x64 tile: strip ss = 2*wg + s2; m<ss full, m==ss masked
        #pragma unroll
        for (int s2 = 0; s2 < 2; ++s2) {
          const int L = 2 * wg + s2;
          for (int m = 0; m < L; ++m) {
            f32x4 sv = fz;
            #pragma unroll
            for (int kk = 0; kk < 2; ++kk) {
              bf16x8 ak = *(const bf16x8*)(&Ks[(m * 16 + lrow) * 64
                                               + (((kk * 4 + quad) ^ (lrow & 7)) << 3)]);
              sv = __builtin_amdgcn_mfma_f32_16x16x32_bf16(ak, bq[s2][kk], sv, 0, 0, 0);
            }
            float p0 = EXP2(sv[0]), p1 = EXP2(sv[1]), p2 = EXP2(sv[2]), p3 = EXP2(sv[3]);
            lsum[s2] += (p0 + p1) + (p2 + p3);
            s16x4 pk = pk4bf(p0, p1, p2, p3);
            const int sq = m * 4 + quad;
            #pragma unroll
            for (int d = 0; d < 4; ++d) {
              int dk = d * 16 + lrow;
              s16x4 av = *(const s16x4*)(&Vs[sq * 256
                                             + ((((dk >> 1) ^ (sq & 7)) << 3) | ((dk & 1) << 2))]);
              oacc[s2][d] = mfma16(av, pk, oacc[s2][d]);
            }
          }
          { // m == L : masked strip (k > q -> 0)
            f32x4 sv = fz;
            #pragma unroll
            for (int kk = 0; kk < 2; ++kk) {
              bf16x8 ak = *(const bf16x8*)(&Ks[(L * 16 + lrow) * 64
                                               + (((kk * 4 + quad) ^ (lrow & 7)) << 3)]);
              sv = __builtin_amdgcn_mfma_f32_16x16x32_bf16(ak, bq[s2][kk], sv, 0, 0, 0);
            }
            float pp[4];
            #pragma unroll
            for (int r = 0; r < 4; ++r)
              pp[r] = (quad * 4 + r > lrow) ? 0.f : EXP2(sv[r]);
            lsum[s2] += (pp[0] + pp[1]) + (pp[2] + pp[3]);
            s16x4 pk = pk4bf(pp[0], pp[1], pp[2], pp[3]);
            const int sq = L * 4 + quad;
            #pragma unroll
            for (int d = 0; d < 4; ++d) {
              int dk = d * 16 + lrow;
              s16x4 av = *(const s16x4*)(&Vs[sq * 256
                                             + ((((dk >> 1) ^ (sq & 7)) << 3) | ((dk & 1) << 2))]);
              oacc[s2][d] = mfma16(av, pk, oacc[s2][d]);
            }
          }
        }
      }
    }

    __syncthreads();                               // step end: staged drained, compute done

    if (s == sAend) {
      EPI(y);                                      // combine + write qA
      #pragma unroll
      for (int s2 = 0; s2 < 2; ++s2) {
        oacc[s2][0] = fz; oacc[s2][1] = fz; oacc[s2][2] = fz; oacc[s2][3] = fz;
        lsum[s2] = 0.f;
      }
      LOADQ(qB);
    } else if (s == 16) {
      EPI(qB);
    }
  }
#undef DEC
#undef STAGE1
#undef LOADQ
}

// ---------------- launch ----------------
extern "C" void kernel_launch(void* const* d_in, const int* in_sizes, int n_in,
                              void* d_out, int out_size, void* d_ws, size_t ws_size,
                              hipStream_t stream) {
  const float* x  = (const float*)d_in[0];
  const float* Wq = (const float*)d_in[1];
  const float* Wk = (const float*)d_in[2];
  const float* Wv = (const float*)d_in[3];
  const float* Wo = (const float*)d_in[4];

  u16* ws = (u16*)d_ws;
  const size_t WSZ = (size_t)DMOD * DMOD;
  const size_t TSZ = (size_t)BAT * NH * SEQ * DKH;
  u16* Wt  = ws;                 // 4 transposed weights
  u16* Wto = Wt + 3 * WSZ;
  u16* xb  = Wt + 4 * WSZ;       // x bf16; dead after QKV -> reused as Ob
  u16* Qb  = xb + TSZ;
  u16* Kb  = Qb + TSZ;
  u16* Vb  = Kb + TSZ;           // [b,h,s/4,dk,4]
  u16* Ob  = xb;

  transpose_all<<<dim3(32, 32, 4), dim3(32, 8), 0, stream>>>(Wq, Wk, Wv, Wo, Wt);
  convert_x<<<dim3(2048), 256, 0, stream>>>(x, xb);

  gemm_qkv<<<dim3(32, 24), 256, 0, stream>>>(xb, Wt, Qb, Kb, Vb);

  attn_k<<<dim3(32, 16), 256, 0, stream>>>(Qb, Kb, Vb, Ob);

  gemm_out<<<dim3(32, 16), 256, 0, stream>>>(Ob, Wto, (float*)d_out);
}

// Round 8
// 164.423 us; speedup vs baseline: 1.7503x; 1.0365x over previous
//
#include <hip/hip_runtime.h>

typedef unsigned short u16;
typedef unsigned int   u32;

using bf16x8 = __attribute__((ext_vector_type(8))) __bf16;
using bf16x4 = __attribute__((ext_vector_type(4))) __bf16;
using f32x4  = __attribute__((ext_vector_type(4))) float;
using s16x4  = __attribute__((ext_vector_type(4))) short;

#define NH    16
#define DKH   64
#define SEQ   2048
#define BAT   2
#define DMOD  1024

// 0.125 (1/sqrt(dk)) * log2(e): scores in log2 domain -> p = exp2(s)
#define QSCALE 0.18033688011112042f

__device__ __forceinline__ u16 f2bf(float f) {
  union { float f; u32 u; } v; v.f = f;
  u32 r = v.u + 0x7fffu + ((v.u >> 16) & 1u);
  return (u16)(r >> 16);
}

__device__ __forceinline__ u32 pack2bf(float a, float b) {
  union { float f; u32 u; } x, y; x.f = a; y.f = b;
  u32 ua = x.u + 0x7fffu + ((x.u >> 16) & 1u);
  u32 ub = y.u + 0x7fffu + ((y.u >> 16) & 1u);
  return __builtin_amdgcn_perm(ub, ua, 0x07060302u);
}

// compiler emits v_cvt_pk_bf16_f32 pairs
__device__ __forceinline__ s16x4 pk4bf(float a, float b, float c, float d) {
  union { bf16x4 bv; s16x4 sv; } u;
  u.bv[0] = (__bf16)a; u.bv[1] = (__bf16)b; u.bv[2] = (__bf16)c; u.bv[3] = (__bf16)d;
  return u.sv;
}

#if __has_builtin(__builtin_amdgcn_exp2f)
#define EXP2(x) __builtin_amdgcn_exp2f(x)
#else
#define EXP2(x) exp2f(x)
#endif

#if __has_builtin(__builtin_amdgcn_mfma_f32_16x16x16bf16_1k)
__device__ __forceinline__ f32x4 mfma16(s16x4 a, s16x4 b, f32x4 c) {
  return __builtin_amdgcn_mfma_f32_16x16x16bf16_1k(a, b, c, 0, 0, 0);
}
#else
__device__ __forceinline__ f32x4 mfma16(s16x4 a, s16x4 b, f32x4 c) {
  f32x4 d;
  asm volatile("v_mfma_f32_16x16x16_bf16 %0, %1, %2, %3\n\ts_nop 7\n\ts_nop 7"
               : "=v"(d) : "v"(a), "v"(b), "v"(c));
  return d;
}
#endif

// async global->LDS, 16B per lane. Dest must be linear in tid within each wave.
typedef const __attribute__((address_space(1))) u32 glb_u32;
typedef __attribute__((address_space(3))) u32 lds_u32;
__device__ __forceinline__ void gload16(const u16* g, u16* l) {
  __builtin_amdgcn_global_load_lds((glb_u32*)(const void*)g, (lds_u32*)(void*)l, 16, 0, 0);
}

// ---------------- fused 4x weight transpose + fp32->bf16 ----------------
__global__ __launch_bounds__(256) void transpose_all(const float* __restrict__ Wq,
                                                     const float* __restrict__ Wk,
                                                     const float* __restrict__ Wv,
                                                     const float* __restrict__ Wo,
                                                     u16* __restrict__ Wt) {
  __shared__ u16 t[32][33];
  const float* W = blockIdx.z == 0 ? Wq : blockIdx.z == 1 ? Wk : blockIdx.z == 2 ? Wv : Wo;
  u16* o = Wt + (size_t)blockIdx.z * DMOD * DMOD;
  int bx = blockIdx.x * 32, by = blockIdx.y * 32;
  int x = threadIdx.x, y = threadIdx.y;
  #pragma unroll
  for (int i = 0; i < 32; i += 8)
    t[y + i][x] = f2bf(W[(size_t)(by + y + i) * DMOD + bx + x]);
  __syncthreads();
  #pragma unroll
  for (int i = 0; i < 32; i += 8)
    o[(size_t)(bx + y + i) * DMOD + by + x] = t[x][y + i];
}

// ---------------- x fp32 -> bf16 ----------------
__global__ __launch_bounds__(256) void convert_x(const float* __restrict__ x,
                                                 u16* __restrict__ xb) {
  size_t i = ((size_t)blockIdx.x * 256 + threadIdx.x) * 8;
  float4 f0 = *(const float4*)(x + i);
  float4 f1 = *(const float4*)(x + i + 4);
  uint4 o;
  o.x = pack2bf(f0.x, f0.y); o.y = pack2bf(f0.z, f0.w);
  o.z = pack2bf(f1.x, f1.y); o.w = pack2bf(f1.z, f1.w);
  *(uint4*)(xb + i) = o;
}

// -------- QKV GEMM: [4096x1024]*[3072x1024]^T, BK=64, gload_lds + XOR swizzle --------
// Round-8: BK 32->64 halves barrier/drain count (32->16 iters), doubles MFMA per drain.
// LDS row stride 128B would be a 32-way bank conflict (G4) -> both-sides 16B-chunk XOR
// swizzle (c ^= r&7 on global source, same XOR on read addr; session-verified in attn:
// conflicts 1.84M->393K). LDS 32KB/block -> still 3 blocks/CU.
__global__ __launch_bounds__(256, 3) void gemm_qkv(const u16* __restrict__ A,
                                                   const u16* __restrict__ Bt,
                                                   u16* __restrict__ Qo,
                                                   u16* __restrict__ Ko,
                                                   u16* __restrict__ Vo) {
  __shared__ __align__(16) u16 As[128 * 64];
  __shared__ __align__(16) u16 Bs[128 * 64];
  const int tid  = threadIdx.x;
  const int lane = tid & 63, wv = tid >> 6;
  const int wm   = wv >> 1, wn = wv & 1;
  const int lrow = lane & 15, quad = lane >> 4;
  const int tileM = blockIdx.x * 128, tileN = blockIdx.y * 128;

  const f32x4 fz = {0.f, 0.f, 0.f, 0.f};
  f32x4 acc[4][4];
  #pragma unroll
  for (int i = 0; i < 4; ++i)
    #pragma unroll
    for (int j = 0; j < 4; ++j) acc[i][j] = fz;

  for (int kt = 0; kt < DMOD; kt += 64) {
    if (kt) __syncthreads();           // previous compute done reading LDS
    #pragma unroll
    for (int i = 0; i < 4; ++i) {
      int idx = i * 256 + tid;         // 1024 chunks of 16B = 128 rows x 128B
      int r = idx >> 3, c = idx & 7;
      gload16(&A [(size_t)(tileM + r) * DMOD + kt + ((c ^ (r & 7)) << 3)], &As[idx * 8]);
      gload16(&Bt[(size_t)(tileN + r) * DMOD + kt + ((c ^ (r & 7)) << 3)], &Bs[idx * 8]);
    }
    __syncthreads();                   // barrier drains vmcnt -> tile visible

    #pragma unroll
    for (int kk = 0; kk < 2; ++kk) {
      bf16x8 af[4], bfr[4];
      #pragma unroll
      for (int mt = 0; mt < 4; ++mt)
        af[mt] = *(const bf16x8*)(&As[(wm * 64 + mt * 16 + lrow) * 64
                                      + (((kk * 4 + quad) ^ (lrow & 7)) << 3)]);
      #pragma unroll
      for (int nt = 0; nt < 4; ++nt)
        bfr[nt] = *(const bf16x8*)(&Bs[(wn * 64 + nt * 16 + lrow) * 64
                                       + (((kk * 4 + quad) ^ (lrow & 7)) << 3)]);
      #pragma unroll
      for (int mt = 0; mt < 4; ++mt)
        #pragma unroll
        for (int nt = 0; nt < 4; ++nt)
          acc[mt][nt] = __builtin_amdgcn_mfma_f32_16x16x32_bf16(af[mt], bfr[nt],
                                                                acc[mt][nt], 0, 0, 0);
    }
  }

  #pragma unroll
  for (int mt = 0; mt < 4; ++mt) {
    #pragma unroll
    for (int nt = 0; nt < 4; ++nt) {
      int gm0 = tileM + wm * 64 + mt * 16 + quad * 4;
      int gn  = tileN + wn * 64 + nt * 16 + lrow;
      int which = gn >> 10, col = gn & 1023;
      int bb = gm0 >> 11, srw0 = gm0 & (SEQ - 1);
      int hh = col >> 6, dki = col & (DKH - 1);
      size_t bhi = (size_t)(bb * NH + hh);
      if (which == 0) {
        #pragma unroll
        for (int r = 0; r < 4; ++r)
          Qo[(bhi * SEQ + srw0 + r) * DKH + dki] = f2bf(acc[mt][nt][r] * QSCALE);
      } else if (which == 1) {
        #pragma unroll
        for (int r = 0; r < 4; ++r)
          Ko[(bhi * SEQ + srw0 + r) * DKH + dki] = f2bf(acc[mt][nt][r]);
      } else {
        uint2 pk;
        pk.x = pack2bf(acc[mt][nt][0], acc[mt][nt][1]);
        pk.y = pack2bf(acc[mt][nt][2], acc[mt][nt][3]);
        *(uint2*)(&Vo[(((bhi * (SEQ / 4)) + (srw0 >> 2)) * DKH + dki) * 4]) = pk;
      }
    }
  }
}

// -------- out GEMM: [4096x1024]*[1024x1024]^T -> fp32, 128x64, BK=64, swizzled --------
__global__ __launch_bounds__(256, 3) void gemm_out(const u16* __restrict__ A,
                                                   const u16* __restrict__ Bt,
                                                   float* __restrict__ Co) {
  __shared__ __align__(16) u16 As[128 * 64];
  __shared__ __align__(16) u16 Bs[64 * 64];
  const int tid  = threadIdx.x;
  const int lane = tid & 63, wv = tid >> 6;
  const int wm   = wv & 1, wn = wv >> 1;
  const int lrow = lane & 15, quad = lane >> 4;
  const int tileM = blockIdx.x * 128, tileN = blockIdx.y * 64;

  const f32x4 fz = {0.f, 0.f, 0.f, 0.f};
  f32x4 acc[4][2];
  #pragma unroll
  for (int i = 0; i < 4; ++i) { acc[i][0] = fz; acc[i][1] = fz; }

  for (int kt = 0; kt < DMOD; kt += 64) {
    if (kt) __syncthreads();
    #pragma unroll
    for (int i = 0; i < 4; ++i) {
      int idx = i * 256 + tid;
      int r = idx >> 3, c = idx & 7;
      gload16(&A[(size_t)(tileM + r) * DMOD + kt + ((c ^ (r & 7)) << 3)], &As[idx * 8]);
    }
    #pragma unroll
    for (int i = 0; i < 2; ++i) {
      int idx = i * 256 + tid;         // 512 chunks = 64 rows x 128B
      int r = idx >> 3, c = idx & 7;
      gload16(&Bt[(size_t)(tileN + r) * DMOD + kt + ((c ^ (r & 7)) << 3)], &Bs[idx * 8]);
    }
    __syncthreads();

    #pragma unroll
    for (int kk = 0; kk < 2; ++kk) {
      bf16x8 af[4], bfr[2];
      #pragma unroll
      for (int mt = 0; mt < 4; ++mt)
        af[mt] = *(const bf16x8*)(&As[(wm * 64 + mt * 16 + lrow) * 64
                                      + (((kk * 4 + quad) ^ (lrow & 7)) << 3)]);
      #pragma unroll
      for (int nt = 0; nt < 2; ++nt)
        bfr[nt] = *(const bf16x8*)(&Bs[(wn * 32 + nt * 16 + lrow) * 64
                                       + (((kk * 4 + quad) ^ (lrow & 7)) << 3)]);
      #pragma unroll
      for (int mt = 0; mt < 4; ++mt)
        #pragma unroll
        for (int nt = 0; nt < 2; ++nt)
          acc[mt][nt] = __builtin_amdgcn_mfma_f32_16x16x32_bf16(af[mt], bfr[nt],
                                                                acc[mt][nt], 0, 0, 0);
    }
  }

  #pragma unroll
  for (int mt = 0; mt < 4; ++mt)
    #pragma unroll
    for (int nt = 0; nt < 2; ++nt)
      #pragma unroll
      for (int r = 0; r < 4; ++r) {
        int gm = tileM + wm * 64 + mt * 16 + quad * 4 + r;
        int gn = tileN + wn * 32 + nt * 16 + lrow;
        Co[(size_t)gm * DMOD + gn] = acc[mt][nt][r];
      }
}

// ------------- causal flash attention: split-k wave-groups, in-LDS combine -------------
// (round-7 structure, best measured — FROZEN this round)
#define OPAD 68

__global__ __launch_bounds__(256, 2) void attn_k(const u16* __restrict__ Q,
                                                 const u16* __restrict__ Kg,
                                                 const u16* __restrict__ Vg,
                                                 u16* __restrict__ Og) {
  __shared__ __align__(16) u16 Ksb[2][2][64 * 64];    // [group][dbuf], swizzled
  __shared__ __align__(16) u16 Vsb[2][2][16 * 256];
  __shared__ __align__(16) u16 Osc[64 * OPAD];        // f32[32][OPAD] / u16[64][OPAD]
  __shared__ float Lsc[32];

  const int tid  = threadIdx.x;
  const int lane = tid & 63, w = tid >> 6;            // w in 0..3
  const int g    = w >> 1,  wg = w & 1;               // group, wave-in-group
  const int lrow = lane & 15, quad = lane >> 4;
  const int bh = blockIdx.x, y = blockIdx.y;          // y in 0..15
  const int b = bh >> 4, h = bh & 15;
  const int qB = 31 - y;
  const int sAend = y >> 1;                           // qA's last step index

  const u16* Qbh = Q  + (size_t)bh * SEQ * DKH;
  const u16* Kbh = Kg + (size_t)bh * SEQ * DKH;
  const u16* Vbh = Vg + (size_t)bh * SEQ * DKH;       // [s/4][dk][4]

  const f32x4 fz = {0.f, 0.f, 0.f, 0.f};
  f32x4 oacc[2][4];
  float lsum[2];
  bf16x8 bq[2][2];

  // decode step s, group gg -> (q-tile, k-tile j, valid)
#define DEC(s_, g_, qt_, j_, v_)                                                   \
  { if ((s_) <= sAend) { qt_ = y;  j_ = 2 * (s_) + (g_);              v_ = (j_ <= y);  } \
    else               { qt_ = qB; j_ = 2 * ((s_) - sAend - 1) + (g_); v_ = (j_ <= qB); } }

  // stage 64-row k-tile j into group gg's buffer p (dest linear, src inverse-swizzled)
#define STAGE1(gg, p_, j_)                                                          \
  { _Pragma("unroll")                                                               \
    for (int i_ = 0; i_ < 2; ++i_) {                                                \
      int cD = i_ * 256 + tid; int r_ = cD >> 3, c_ = cD & 7;                       \
      gload16(&Kbh[(size_t)((j_) * 64 + r_) * DKH + ((c_ ^ (r_ & 7)) << 3)],        \
              &Ksb[gg][p_][cD * 8]); }                                              \
    _Pragma("unroll")                                                               \
    for (int i_ = 0; i_ < 2; ++i_) {                                                \
      int cD = i_ * 256 + tid; int sq_ = cD >> 5, c_ = cD & 31;                     \
      gload16(&Vbh[(size_t)((j_) * 16 + sq_) * 256 + ((c_ ^ (sq_ & 7)) << 3)],      \
              &Vsb[gg][p_][cD * 8]); } }

#define LOADQ(qt_)                                                                  \
  { _Pragma("unroll")                                                               \
    for (int s_ = 0; s_ < 2; ++s_)                                                  \
      _Pragma("unroll")                                                             \
      for (int kk_ = 0; kk_ < 2; ++kk_)                                             \
        bq[s_][kk_] = *(const bf16x8*)(&Qbh[(size_t)((qt_) * 64 + wg * 32 + s_ * 16 \
                                            + lrow) * DKH + kk_ * 32 + quad * 8]); }

  // per-q-tile epilogue: group1 -> LDS partials (2 phases), group0 combines+writes
  auto EPI = [&](int qt) {
    float ls[2];
    #pragma unroll
    for (int s2 = 0; s2 < 2; ++s2) {
      float v = lsum[s2];
      v += __shfl_xor(v, 16, 64);
      v += __shfl_xor(v, 32, 64);
      ls[s2] = v;
    }
    float* OscF = (float*)Osc;
    #pragma unroll
    for (int ph = 0; ph < 2; ++ph) {
      if (g == 1) {
        int srow = wg * 16 + lrow;
        #pragma unroll
        for (int d = 0; d < 4; ++d)
          *(f32x4*)(&OscF[srow * OPAD + d * 16 + quad * 4]) = oacc[ph][d];
        if (quad == 0) Lsc[srow] = ls[ph];
      }
      __syncthreads();
      if (g == 0) {
        int srow = wg * 16 + lrow;
        ls[ph] += Lsc[srow];
        #pragma unroll
        for (int d = 0; d < 4; ++d) {
          f32x4 ov = *(const f32x4*)(&OscF[srow * OPAD + d * 16 + quad * 4]);
          oacc[ph][d] += ov;
        }
      }
      __syncthreads();
    }
    if (g == 0) {
      #pragma unroll
      for (int s2 = 0; s2 < 2; ++s2) {
        float inv = 1.f / ls[s2];
        int row = wg * 32 + s2 * 16 + lrow;
        #pragma unroll
        for (int d = 0; d < 4; ++d) {
          uint2 pkk;
          pkk.x = pack2bf(oacc[s2][d][0] * inv, oacc[s2][d][1] * inv);
          pkk.y = pack2bf(oacc[s2][d][2] * inv, oacc[s2][d][3] * inv);
          *(uint2*)(&Osc[row * OPAD + d * 16 + quad * 4]) = pkk;
        }
      }
    }
    __syncthreads();
    #pragma unroll
    for (int k2 = 0; k2 < 2; ++k2) {
      int c2 = k2 * 256 + tid;                    // 512 chunks = 64 rows x 128B
      int row = c2 >> 3, ch = c2 & 7;
      uint4 vv = *(const uint4*)(&Osc[row * OPAD + ch * 8]);
      *(uint4*)(&Og[(size_t)(b * SEQ + qt * 64 + row) * DMOD + h * DKH + ch * 8]) = vv;
    }
  };

  // ---- prologue: stage step-0 tiles, load qA fragments ----
  { int qt0, j0; bool v0;
    DEC(0, 0, qt0, j0, v0); if (v0) STAGE1(0, 0, j0);
    DEC(0, 1, qt0, j0, v0); if (v0) STAGE1(1, 0, j0);
  }
  LOADQ(y);
  #pragma unroll
  for (int s2 = 0; s2 < 2; ++s2) {
    oacc[s2][0] = fz; oacc[s2][1] = fz; oacc[s2][2] = fz; oacc[s2][3] = fz;
    lsum[s2] = 0.f;
  }
  __syncthreads();                                 // drain -> step-0 tiles ready

  for (int s = 0; s <= 16; ++s) {
    const int p = s & 1;

    if (s < 16) {                                  // issue next-step tiles (both groups)
      int qtn, jn; bool vn;
      DEC(s + 1, 0, qtn, jn, vn); if (vn) STAGE1(0, p ^ 1, jn);
      DEC(s + 1, 1, qtn, jn, vn); if (vn) STAGE1(1, p ^ 1, jn);
    }

    int qt, j; bool valid;
    DEC(s, g, qt, j, valid);
    if (valid) {
      const u16* Ks = Ksb[g][p];
      const u16* Vs = Vsb[g][p];
      if (j < qt) {
        __builtin_amdgcn_s_setprio(1);
        f32x4 sacc[2][4];
        #pragma unroll
        for (int s2 = 0; s2 < 2; ++s2)
          #pragma unroll
          for (int m = 0; m < 4; ++m) sacc[s2][m] = fz;
        #pragma unroll
        for (int kk = 0; kk < 2; ++kk)
          #pragma unroll
          for (int m = 0; m < 4; ++m) {
            bf16x8 ak = *(const bf16x8*)(&Ks[(m * 16 + lrow) * 64
                                             + (((kk * 4 + quad) ^ (lrow & 7)) << 3)]);
            sacc[0][m] = __builtin_amdgcn_mfma_f32_16x16x32_bf16(ak, bq[0][kk], sacc[0][m], 0, 0, 0);
            sacc[1][m] = __builtin_amdgcn_mfma_f32_16x16x32_bf16(ak, bq[1][kk], sacc[1][m], 0, 0, 0);
          }
        #pragma unroll
        for (int m = 0; m < 4; ++m) {
          float p00 = EXP2(sacc[0][m][0]), p01 = EXP2(sacc[0][m][1]);
          float p02 = EXP2(sacc[0][m][2]), p03 = EXP2(sacc[0][m][3]);
          float p10 = EXP2(sacc[1][m][0]), p11 = EXP2(sacc[1][m][1]);
          float p12 = EXP2(sacc[1][m][2]), p13 = EXP2(sacc[1][m][3]);
          lsum[0] += (p00 + p01) + (p02 + p03);
          lsum[1] += (p10 + p11) + (p12 + p13);
          s16x4 pk0 = pk4bf(p00, p01, p02, p03);
          s16x4 pk1 = pk4bf(p10, p11, p12, p13);
          const int sq = m * 4 + quad;
          #pragma unroll
          for (int d = 0; d < 4; ++d) {
            int dk = d * 16 + lrow;
            s16x4 av = *(const s16x4*)(&Vs[sq * 256
                                           + ((((dk >> 1) ^ (sq & 7)) << 3) | ((dk & 1) << 2))]);
            oacc[0][d] = mfma16(av, pk0, oacc[0][d]);
            oacc[1][d] = mfma16(av, pk1, oacc[1][d]);
          }
        }
        __builtin_amdgcn_s_setprio(0);
      } else {
        // diagonal 64x64 tile: strip ss = 2*wg + s2; m<ss full, m==ss masked
        #pragma unroll
        for (int s2 = 0; s2 < 2; ++s2) {
          const int L = 2 * wg + s2;
          for (int m = 0; m < L; ++m) {
            f32x4 sv = fz;
            #pragma unroll
            for (int kk = 0; kk < 2; ++kk) {
              bf16x8 ak = *(const bf16x8*)(&Ks[(m * 16 + lrow) * 64
                                               + (((kk * 4 + quad) ^ (lrow & 7)) << 3)]);
              sv = __builtin_amdgcn_mfma_f32_16x16x32_bf16(ak, bq[s2][kk], sv, 0, 0, 0);
            }
            float p0 = EXP2(sv[0]), p1 = EXP2(sv[1]), p2 = EXP2(sv[2]), p3 = EXP2(sv[3]);
            lsum[s2] += (p0 + p1) + (p2 + p3);
            s16x4 pk = pk4bf(p0, p1, p2, p3);
            const int sq = m * 4 + quad;
            #pragma unroll
            for (int d = 0; d < 4; ++d) {
              int dk = d * 16 + lrow;
              s16x4 av = *(const s16x4*)(&Vs[sq * 256
                                             + ((((dk >> 1) ^ (sq & 7)) << 3) | ((dk & 1) << 2))]);
              oacc[s2][d] = mfma16(av, pk, oacc[s2][d]);
            }
          }
          { // m == L : masked strip (k > q -> 0)
            f32x4 sv = fz;
            #pragma unroll
            for (int kk = 0; kk < 2; ++kk) {
              bf16x8 ak = *(const bf16x8*)(&Ks[(L * 16 + lrow) * 64
                                               + (((kk * 4 + quad) ^ (lrow & 7)) << 3)]);
              sv = __builtin_amdgcn_mfma_f32_16x16x32_bf16(ak, bq[s2][kk], sv, 0, 0, 0);
            }
            float pp[4];
            #pragma unroll
            for (int r = 0; r < 4; ++r)
              pp[r] = (quad * 4 + r > lrow) ? 0.f : EXP2(sv[r]);
            lsum[s2] += (pp[0] + pp[1]) + (pp[2] + pp[3]);
            s16x4 pk = pk4bf(pp[0], pp[1], pp[2], pp[3]);
            const int sq = L * 4 + quad;
            #pragma unroll
            for (int d = 0; d < 4; ++d) {
              int dk = d * 16 + lrow;
              s16x4 av = *(const s16x4*)(&Vs[sq * 256
                                             + ((((dk >> 1) ^ (sq & 7)) << 3) | ((dk & 1) << 2))]);
              oacc[s2][d] = mfma16(av, pk, oacc[s2][d]);
            }
          }
        }
      }
    }

    __syncthreads();                               // step end: staged drained, compute done

    if (s == sAend) {
      EPI(y);                                      // combine + write qA
      #pragma unroll
      for (int s2 = 0; s2 < 2; ++s2) {
        oacc[s2][0] = fz; oacc[s2][1] = fz; oacc[s2][2] = fz; oacc[s2][3] = fz;
        lsum[s2] = 0.f;
      }
      LOADQ(qB);
    } else if (s == 16) {
      EPI(qB);
    }
  }
#undef DEC
#undef STAGE1
#undef LOADQ
}

// ---------------- launch ----------------
extern "C" void kernel_launch(void* const* d_in, const int* in_sizes, int n_in,
                              void* d_out, int out_size, void* d_ws, size_t ws_size,
                              hipStream_t stream) {
  const float* x  = (const float*)d_in[0];
  const float* Wq = (const float*)d_in[1];
  const float* Wk = (const float*)d_in[2];
  const float* Wv = (const float*)d_in[3];
  const float* Wo = (const float*)d_in[4];

  u16* ws = (u16*)d_ws;
  const size_t WSZ = (size_t)DMOD * DMOD;
  const size_t TSZ = (size_t)BAT * NH * SEQ * DKH;
  u16* Wt  = ws;                 // 4 transposed weights
  u16* Wto = Wt + 3 * WSZ;
  u16* xb  = Wt + 4 * WSZ;       // x bf16; dead after QKV -> reused as Ob
  u16* Qb  = xb + TSZ;
  u16* Kb  = Qb + TSZ;
  u16* Vb  = Kb + TSZ;           // [b,h,s/4,dk,4]
  u16* Ob  = xb;

  transpose_all<<<dim3(32, 32, 4), dim3(32, 8), 0, stream>>>(Wq, Wk, Wv, Wo, Wt);
  convert_x<<<dim3(2048), 256, 0, stream>>>(x, xb);

  gemm_qkv<<<dim3(32, 24), 256, 0, stream>>>(xb, Wt, Qb, Kb, Vb);

  attn_k<<<dim3(32, 16), 256, 0, stream>>>(Qb, Kb, Vb, Ob);

  gemm_out<<<dim3(32, 16), 256, 0, stream>>>(Ob, Wto, (float*)d_out);
}